// Round 1
// baseline (987.622 us; speedup 1.0000x reference)
//
#include <hip/hip_runtime.h>
#include <math.h>

#define BATCH 8192

__device__ __forceinline__ float sigm(float v) { return 1.0f / (1.0f + __expf(-v)); }

// ---------------- Kernel A: STFT (conv1d stride 128, K=256) + magnitude ----------------
// grid 2048, block 256, 4 batches/block. mag layout: [b][t][c], idx = b*516 + t*129 + c
__global__ __launch_bounds__(256) void k_stft(const float* __restrict__ audio,
                                              const float* __restrict__ fb,
                                              float* __restrict__ mag) {
    __shared__ float xs[4][640];
    const int tid = threadIdx.x;
    const int b0 = blockIdx.x << 2;
    for (int i = tid; i < 4 * 576; i += 256) {
        int bl = i / 576, jx = i - bl * 576;
        xs[bl][jx] = audio[(size_t)(b0 + bl) * 576 + jx];
    }
    __syncthreads();
    {   // reflect pad: xpad[576+j] = audio[574-j], j=0..63
        int bl = tid >> 6, jx = tid & 63;
        xs[bl][576 + jx] = xs[bl][574 - jx];
    }
    __syncthreads();
    for (int o = tid; o < 516; o += 256) {
        const int t = o / 129;
        const int c = o - t * 129;
        const float4* fr = (const float4*)(fb + (size_t)c * 256);
        const float4* fi = (const float4*)(fb + (size_t)(129 + c) * 256);
        const float4* x0 = (const float4*)(&xs[0][t * 128]);
        const float4* x1 = (const float4*)(&xs[1][t * 128]);
        const float4* x2 = (const float4*)(&xs[2][t * 128]);
        const float4* x3 = (const float4*)(&xs[3][t * 128]);
        float r0 = 0.f, r1 = 0.f, r2 = 0.f, r3 = 0.f;
        float q0 = 0.f, q1 = 0.f, q2 = 0.f, q3 = 0.f;
        #pragma unroll 8
        for (int k = 0; k < 64; ++k) {
            const float4 fv = fr[k];
            const float4 gv = fi[k];
            float4 a;
            a = x0[k];
            r0 += fv.x*a.x + fv.y*a.y + fv.z*a.z + fv.w*a.w;
            q0 += gv.x*a.x + gv.y*a.y + gv.z*a.z + gv.w*a.w;
            a = x1[k];
            r1 += fv.x*a.x + fv.y*a.y + fv.z*a.z + fv.w*a.w;
            q1 += gv.x*a.x + gv.y*a.y + gv.z*a.z + gv.w*a.w;
            a = x2[k];
            r2 += fv.x*a.x + fv.y*a.y + fv.z*a.z + fv.w*a.w;
            q2 += gv.x*a.x + gv.y*a.y + gv.z*a.z + gv.w*a.w;
            a = x3[k];
            r3 += fv.x*a.x + fv.y*a.y + fv.z*a.z + fv.w*a.w;
            q3 += gv.x*a.x + gv.y*a.y + gv.z*a.z + gv.w*a.w;
        }
        mag[(size_t)(b0 + 0) * 516 + o] = sqrtf(r0*r0 + q0*q0);
        mag[(size_t)(b0 + 1) * 516 + o] = sqrtf(r1*r1 + q1*q1);
        mag[(size_t)(b0 + 2) * 516 + o] = sqrtf(r2*r2 + q2*q2);
        mag[(size_t)(b0 + 3) * 516 + o] = sqrtf(r3*r3 + q3*q3);
    }
}

// ---------------- Kernel B: enc1 conv (129ch -> 128ch, k=3, pad=1) + relu ----------------
// grid 2048, block 256, 4 batches/block. e1 layout: [b][t][oc], idx = b*512 + t*128 + oc
__global__ __launch_bounds__(256) void k_enc1(const float* __restrict__ mag,
                                              const float* __restrict__ w1,
                                              const float* __restrict__ b1,
                                              float* __restrict__ e1) {
    __shared__ float ms[4][516];
    const int tid = threadIdx.x;
    const int b0 = blockIdx.x << 2;
    for (int i = tid; i < 4 * 516; i += 256) {
        int bl = i / 516, jx = i - bl * 516;
        ms[bl][jx] = mag[(size_t)(b0 + bl) * 516 + jx];
    }
    __syncthreads();
    for (int o = tid; o < 512; o += 256) {
        const int t = o >> 7, oc = o & 127;
        const float bias = b1[oc];
        float a0 = bias, a1 = bias, a2 = bias, a3 = bias;
        const float* wrow = w1 + (size_t)oc * 129 * 3;
        const bool h0 = (t > 0), h2 = (t < 3);
        const int r0 = h0 ? (t - 1) * 129 : 0;
        const int r1 = t * 129;
        const int r2 = h2 ? (t + 1) * 129 : 0;
        const float z0 = h0 ? 1.f : 0.f, z2 = h2 ? 1.f : 0.f;
        for (int ic = 0; ic < 129; ++ic) {
            const float w0 = wrow[ic * 3 + 0] * z0;
            const float wm = wrow[ic * 3 + 1];
            const float w2 = wrow[ic * 3 + 2] * z2;
            a0 += w0 * ms[0][r0 + ic] + wm * ms[0][r1 + ic] + w2 * ms[0][r2 + ic];
            a1 += w0 * ms[1][r0 + ic] + wm * ms[1][r1 + ic] + w2 * ms[1][r2 + ic];
            a2 += w0 * ms[2][r0 + ic] + wm * ms[2][r1 + ic] + w2 * ms[2][r2 + ic];
            a3 += w0 * ms[3][r0 + ic] + wm * ms[3][r1 + ic] + w2 * ms[3][r2 + ic];
        }
        e1[(size_t)(b0 + 0) * 512 + o] = fmaxf(a0, 0.f);
        e1[(size_t)(b0 + 1) * 512 + o] = fmaxf(a1, 0.f);
        e1[(size_t)(b0 + 2) * 512 + o] = fmaxf(a2, 0.f);
        e1[(size_t)(b0 + 3) * 512 + o] = fmaxf(a3, 0.f);
    }
}

// ---------------- Kernel C: enc2 (s2) + enc3 (s2) + enc4 fused ----------------
// grid 2048, block 256, 4 batches/block. xout layout: [b][oc], idx = b*128 + oc
__global__ __launch_bounds__(256) void k_enc234(const float* __restrict__ e1,
                                                const float* __restrict__ w2, const float* __restrict__ b2,
                                                const float* __restrict__ w3, const float* __restrict__ b3,
                                                const float* __restrict__ w4, const float* __restrict__ b4,
                                                float* __restrict__ xout) {
    __shared__ float s1[4][512];
    __shared__ float s2[4][128];   // [u*64 + ch]
    __shared__ float s3[4][64];
    const int tid = threadIdx.x;
    const int b0 = blockIdx.x << 2;
    for (int i = tid; i < 4 * 512; i += 256) {
        int bl = i >> 9, jx = i & 511;
        s1[bl][jx] = e1[(size_t)(b0 + bl) * 512 + jx];
    }
    __syncthreads();
    // enc2: stride 2, pad 1, input len 4 -> output len 2 (u=0: taps kk=1,2 -> t=0,1; u=1: kk=0,1,2 -> t=1,2,3)
    for (int o = tid; o < 512; o += 256) {
        const int bl = o >> 7, rest = o & 127, u = rest >> 6, oc = rest & 63;
        float acc = b2[oc];
        const float* wrow = w2 + (size_t)oc * 128 * 3;
        if (u == 0) {
            for (int ic = 0; ic < 128; ++ic)
                acc += wrow[ic * 3 + 1] * s1[bl][ic] + wrow[ic * 3 + 2] * s1[bl][128 + ic];
        } else {
            for (int ic = 0; ic < 128; ++ic)
                acc += wrow[ic * 3 + 0] * s1[bl][128 + ic]
                     + wrow[ic * 3 + 1] * s1[bl][256 + ic]
                     + wrow[ic * 3 + 2] * s1[bl][384 + ic];
        }
        s2[bl][rest] = fmaxf(acc, 0.f);
    }
    __syncthreads();
    // enc3: stride 2, pad 1, input len 2 -> len 1 (taps kk=1,2 -> u=0,1)
    {
        const int bl = tid >> 6, oc = tid & 63;
        float acc = b3[oc];
        const float* wrow = w3 + (size_t)oc * 64 * 3;
        for (int ic = 0; ic < 64; ++ic)
            acc += wrow[ic * 3 + 1] * s2[bl][ic] + wrow[ic * 3 + 2] * s2[bl][64 + ic];
        s3[bl][oc] = fmaxf(acc, 0.f);
    }
    __syncthreads();
    // enc4: stride 1, pad 1, input len 1 -> len 1 (only kk=1 valid)
    for (int o = tid; o < 512; o += 256) {
        const int bl = o >> 7, oc = o & 127;
        float acc = b4[oc];
        const float* wrow = w4 + (size_t)oc * 64 * 3;
        for (int ic = 0; ic < 64; ++ic)
            acc += wrow[ic * 3 + 1] * s3[bl][ic];
        xout[(size_t)(b0 + bl) * 128 + oc] = fmaxf(acc, 0.f);
    }
}

// ---------------- Kernel D: LSTM cell + head ----------------
// grid 1024, block 256, 8 batches/block (two halves of the block each own 4 batches)
__device__ __forceinline__ void gate_mm(const float* __restrict__ W, const float* __restrict__ U,
                                        const float (*xsh)[128], const float (*hsh)[128],
                                        int blb, int j, float bias, float out[4]) {
    const float4* Wv = (const float4*)(W + (size_t)j * 128);
    const float4* Uv = (const float4*)(U + (size_t)j * 128);
    float a0 = bias, a1 = bias, a2 = bias, a3 = bias;
    #pragma unroll 4
    for (int k = 0; k < 32; ++k) {
        const float4 w = Wv[k];
        const float4 u = Uv[k];
        float4 v;
        v = ((const float4*)xsh[blb + 0])[k]; a0 += w.x*v.x + w.y*v.y + w.z*v.z + w.w*v.w;
        v = ((const float4*)hsh[blb + 0])[k]; a0 += u.x*v.x + u.y*v.y + u.z*v.z + u.w*v.w;
        v = ((const float4*)xsh[blb + 1])[k]; a1 += w.x*v.x + w.y*v.y + w.z*v.z + w.w*v.w;
        v = ((const float4*)hsh[blb + 1])[k]; a1 += u.x*v.x + u.y*v.y + u.z*v.z + u.w*v.w;
        v = ((const float4*)xsh[blb + 2])[k]; a2 += w.x*v.x + w.y*v.y + w.z*v.z + w.w*v.w;
        v = ((const float4*)hsh[blb + 2])[k]; a2 += u.x*v.x + u.y*v.y + u.z*v.z + u.w*v.w;
        v = ((const float4*)xsh[blb + 3])[k]; a3 += w.x*v.x + w.y*v.y + w.z*v.z + w.w*v.w;
        v = ((const float4*)hsh[blb + 3])[k]; a3 += u.x*v.x + u.y*v.y + u.z*v.z + u.w*v.w;
    }
    out[0] = a0; out[1] = a1; out[2] = a2; out[3] = a3;
}

__global__ __launch_bounds__(256) void k_lstm(const float* __restrict__ x,
                                              const float* __restrict__ hin, const float* __restrict__ cin,
                                              const float* __restrict__ wi, const float* __restrict__ wf,
                                              const float* __restrict__ wg, const float* __restrict__ wo,
                                              const float* __restrict__ ui, const float* __restrict__ uf,
                                              const float* __restrict__ ug, const float* __restrict__ uo,
                                              const float* __restrict__ bxi, const float* __restrict__ bxf,
                                              const float* __restrict__ bxg, const float* __restrict__ bxo,
                                              const float* __restrict__ bhi, const float* __restrict__ bhf,
                                              const float* __restrict__ bhg, const float* __restrict__ bho,
                                              const float* __restrict__ cw, const float* __restrict__ cb,
                                              float* __restrict__ out) {
    __shared__ float xsh[8][128];
    __shared__ float hsh[8][128];
    __shared__ float red[8][128];
    const int tid = threadIdx.x;
    const int b0 = blockIdx.x << 3;
    for (int i = tid; i < 8 * 128; i += 256) {
        int bl = i >> 7, jx = i & 127;
        xsh[bl][jx] = x[(size_t)(b0 + bl) * 128 + jx];
        hsh[bl][jx] = hin[(size_t)(b0 + bl) * 128 + jx];
    }
    __syncthreads();
    const int g = tid >> 7;      // 0..1: which 4-batch group
    const int j = tid & 127;     // hidden unit
    const int blb = g << 2;
    float pi[4], pf[4], pg[4], po[4];
    gate_mm(wi, ui, xsh, hsh, blb, j, bxi[j] + bhi[j], pi);
    gate_mm(wf, uf, xsh, hsh, blb, j, bxf[j] + bhf[j], pf);
    gate_mm(wg, ug, xsh, hsh, blb, j, bxg[j] + bhg[j], pg);
    gate_mm(wo, uo, xsh, hsh, blb, j, bxo[j] + bho[j], po);
    const float cwj = cw[j];
    #pragma unroll
    for (int bb = 0; bb < 4; ++bb) {
        const int b = b0 + blb + bb;
        const float ig = sigm(pi[bb]);
        const float fg = sigm(pf[bb]);
        const float gg = tanhf(pg[bb]);
        const float og = sigm(po[bb]);
        const float ci = cin[(size_t)b * 128 + j];
        const float co = fg * ci + ig * gg;
        const float ho = og * tanhf(co);
        out[(size_t)BATCH + (size_t)b * 128 + j] = ho;                         // h_out
        out[(size_t)BATCH + (size_t)BATCH * 128 + (size_t)b * 128 + j] = co;   // c_out
        red[blb + bb][j] = fmaxf(ho, 0.f) * cwj;
    }
    __syncthreads();
    if (tid < 8) {
        float s = 0.f;
        for (int k = 0; k < 128; ++k) s += red[tid][k];
        out[b0 + tid] = sigm(s + cb[0]);                                       // prob
    }
}

extern "C" void kernel_launch(void* const* d_in, const int* in_sizes, int n_in,
                              void* d_out, int out_size, void* d_ws, size_t ws_size,
                              hipStream_t stream) {
    const float* audio = (const float*)d_in[0];
    const float* hin   = (const float*)d_in[1];
    const float* cin   = (const float*)d_in[2];
    const float* fb    = (const float*)d_in[3];
    const float* w1    = (const float*)d_in[4];
    const float* b1    = (const float*)d_in[5];
    const float* w2    = (const float*)d_in[6];
    const float* b2    = (const float*)d_in[7];
    const float* w3    = (const float*)d_in[8];
    const float* b3    = (const float*)d_in[9];
    const float* w4    = (const float*)d_in[10];
    const float* b4    = (const float*)d_in[11];
    const float* wi    = (const float*)d_in[12];
    const float* wf    = (const float*)d_in[13];
    const float* wg    = (const float*)d_in[14];
    const float* wo    = (const float*)d_in[15];
    const float* ui    = (const float*)d_in[16];
    const float* uf    = (const float*)d_in[17];
    const float* ug    = (const float*)d_in[18];
    const float* uo    = (const float*)d_in[19];
    const float* bxi   = (const float*)d_in[20];
    const float* bxf   = (const float*)d_in[21];
    const float* bxg   = (const float*)d_in[22];
    const float* bxo   = (const float*)d_in[23];
    const float* bhi   = (const float*)d_in[24];
    const float* bhf   = (const float*)d_in[25];
    const float* bhg   = (const float*)d_in[26];
    const float* bho   = (const float*)d_in[27];
    const float* cw    = (const float*)d_in[28];
    const float* cb    = (const float*)d_in[29];
    float* out = (float*)d_out;

    float* ws  = (float*)d_ws;
    float* mag  = ws;                          // 8192*516 floats
    float* e1   = mag + (size_t)BATCH * 516;   // 8192*512 floats
    float* xbuf = e1 + (size_t)BATCH * 512;    // 8192*128 floats

    k_stft<<<BATCH / 4, 256, 0, stream>>>(audio, fb, mag);
    k_enc1<<<BATCH / 4, 256, 0, stream>>>(mag, w1, b1, e1);
    k_enc234<<<BATCH / 4, 256, 0, stream>>>(e1, w2, b2, w3, b3, w4, b4, xbuf);
    k_lstm<<<BATCH / 8, 256, 0, stream>>>(xbuf, hin, cin,
                                          wi, wf, wg, wo, ui, uf, ug, uo,
                                          bxi, bxf, bxg, bxo, bhi, bhf, bhg, bho,
                                          cw, cb, out);
}

// Round 2
// 480.381 us; speedup vs baseline: 2.0559x; 2.0559x over previous
//
#include <hip/hip_runtime.h>
#include <math.h>

#define BATCH 8192

__device__ __forceinline__ float sigm(float v) { return 1.0f / (1.0f + __expf(-v)); }

// ---------------- Kernel P: transpose all weights so channel dim is contiguous ----------------
// fbT  [k=0..255][c=0..257]           = fb[c*256 + k]                (66048)
// w1T  [r=0..386][oc=0..127]          = w1[oc*387 + r]               (49536)
// w2T  [r=0..383][oc=0..63]           = w2[oc*384 + r]               (24576)
// w3T  [r=0..191][oc=0..63]           = w3[oc*192 + r]               (12288)
// w4T  [r=0..191][oc=0..127]          = w4[oc*192 + r]               (24576)
// WT   [m=0..7][k=0..127][j=0..127]   = Wm[j*128 + k]                (131072)
#define N_FBT 66048
#define N_W1T 49536
#define N_W2T 24576
#define N_W3T 12288
#define N_W4T 24576
#define N_WT  131072
#define N_PREP (N_FBT + N_W1T + N_W2T + N_W3T + N_W4T + N_WT)

__global__ __launch_bounds__(256) void k_prep(const float* __restrict__ fb,
                                              const float* __restrict__ w1,
                                              const float* __restrict__ w2,
                                              const float* __restrict__ w3,
                                              const float* __restrict__ w4,
                                              const float* __restrict__ wi, const float* __restrict__ wf,
                                              const float* __restrict__ wg, const float* __restrict__ wo,
                                              const float* __restrict__ ui, const float* __restrict__ uf,
                                              const float* __restrict__ ug, const float* __restrict__ uo,
                                              float* __restrict__ fbT, float* __restrict__ w1T,
                                              float* __restrict__ w2T, float* __restrict__ w3T,
                                              float* __restrict__ w4T, float* __restrict__ WT) {
    const float* Ws[8] = {wi, wf, wg, wo, ui, uf, ug, uo};
    for (int i = blockIdx.x * 256 + threadIdx.x; i < N_PREP; i += gridDim.x * 256) {
        int r = i;
        if (r < N_FBT) {
            int k = r / 258, c = r - k * 258;
            fbT[r] = fb[c * 256 + k];
            continue;
        }
        r -= N_FBT;
        if (r < N_W1T) {
            int rr = r >> 7, oc = r & 127;
            w1T[r] = w1[oc * 387 + rr];
            continue;
        }
        r -= N_W1T;
        if (r < N_W2T) {
            int rr = r >> 6, oc = r & 63;
            w2T[r] = w2[oc * 384 + rr];
            continue;
        }
        r -= N_W2T;
        if (r < N_W3T) {
            int rr = r >> 6, oc = r & 63;
            w3T[r] = w3[oc * 192 + rr];
            continue;
        }
        r -= N_W3T;
        if (r < N_W4T) {
            int rr = r >> 7, oc = r & 127;
            w4T[r] = w4[oc * 192 + rr];
            continue;
        }
        r -= N_W4T;
        {
            int m = r >> 14, rem = r & 16383;
            int k = rem >> 7, j = rem & 127;
            WT[r] = Ws[m][j * 128 + k];
        }
    }
}

// ---------------- Kernel A: STFT (conv1d stride 128, K=256) + magnitude ----------------
// grid 2048, block 256, 4 batches/block. mag layout: [b][t][c], idx = b*516 + t*129 + c
// fbT[k*258 + c] (real), fbT[k*258 + 129 + c] (imag): lane-consecutive loads.
__global__ __launch_bounds__(256) void k_stft(const float* __restrict__ audio,
                                              const float* __restrict__ fbT,
                                              float* __restrict__ mag) {
    __shared__ float xs[4][640];
    const int tid = threadIdx.x;
    const int b0 = blockIdx.x << 2;
    for (int i = tid; i < 4 * 576; i += 256) {
        int bl = i / 576, jx = i - bl * 576;
        xs[bl][jx] = audio[(size_t)(b0 + bl) * 576 + jx];
    }
    __syncthreads();
    {   // reflect pad: xpad[576+j] = audio[574-j], j=0..63
        int bl = tid >> 6, jx = tid & 63;
        xs[bl][576 + jx] = xs[bl][574 - jx];
    }
    __syncthreads();
    for (int o = tid; o < 516; o += 256) {
        const int t = o / 129;
        const int c = o - t * 129;
        const float* base = fbT + c;
        const int x0 = t * 128;
        float r0 = 0.f, r1 = 0.f, r2 = 0.f, r3 = 0.f;
        float q0 = 0.f, q1 = 0.f, q2 = 0.f, q3 = 0.f;
        #pragma unroll 8
        for (int k = 0; k < 256; ++k) {
            const float wr = base[(size_t)k * 258];
            const float wq = base[(size_t)k * 258 + 129];
            const float a0 = xs[0][x0 + k];
            const float a1 = xs[1][x0 + k];
            const float a2 = xs[2][x0 + k];
            const float a3 = xs[3][x0 + k];
            r0 += wr * a0; q0 += wq * a0;
            r1 += wr * a1; q1 += wq * a1;
            r2 += wr * a2; q2 += wq * a2;
            r3 += wr * a3; q3 += wq * a3;
        }
        mag[(size_t)(b0 + 0) * 516 + o] = sqrtf(r0*r0 + q0*q0);
        mag[(size_t)(b0 + 1) * 516 + o] = sqrtf(r1*r1 + q1*q1);
        mag[(size_t)(b0 + 2) * 516 + o] = sqrtf(r2*r2 + q2*q2);
        mag[(size_t)(b0 + 3) * 516 + o] = sqrtf(r3*r3 + q3*q3);
    }
}

// ---------------- Kernel B: enc1 conv (129ch -> 128ch, k=3, pad=1) + relu ----------------
// grid 2048, block 256, 4 batches/block. e1 layout: [b][t][oc], idx = b*512 + t*128 + oc
__global__ __launch_bounds__(256) void k_enc1(const float* __restrict__ mag,
                                              const float* __restrict__ w1T,
                                              const float* __restrict__ b1,
                                              float* __restrict__ e1) {
    __shared__ float ms[4][516];
    const int tid = threadIdx.x;
    const int b0 = blockIdx.x << 2;
    for (int i = tid; i < 4 * 516; i += 256) {
        int bl = i / 516, jx = i - bl * 516;
        ms[bl][jx] = mag[(size_t)(b0 + bl) * 516 + jx];
    }
    __syncthreads();
    for (int o = tid; o < 512; o += 256) {
        const int t = o >> 7, oc = o & 127;
        const float bias = b1[oc];
        float a0 = bias, a1 = bias, a2 = bias, a3 = bias;
        const bool h0 = (t > 0), h2 = (t < 3);
        const int r0 = h0 ? (t - 1) * 129 : 0;
        const int r1 = t * 129;
        const int r2 = h2 ? (t + 1) * 129 : 0;
        const float z0 = h0 ? 1.f : 0.f, z2 = h2 ? 1.f : 0.f;
        const float* wp = w1T + oc;
        #pragma unroll 3
        for (int ic = 0; ic < 129; ++ic) {
            const float w0 = wp[(size_t)(ic * 3 + 0) * 128] * z0;
            const float wm = wp[(size_t)(ic * 3 + 1) * 128];
            const float w2 = wp[(size_t)(ic * 3 + 2) * 128] * z2;
            a0 += w0 * ms[0][r0 + ic] + wm * ms[0][r1 + ic] + w2 * ms[0][r2 + ic];
            a1 += w0 * ms[1][r0 + ic] + wm * ms[1][r1 + ic] + w2 * ms[1][r2 + ic];
            a2 += w0 * ms[2][r0 + ic] + wm * ms[2][r1 + ic] + w2 * ms[2][r2 + ic];
            a3 += w0 * ms[3][r0 + ic] + wm * ms[3][r1 + ic] + w2 * ms[3][r2 + ic];
        }
        e1[(size_t)(b0 + 0) * 512 + o] = fmaxf(a0, 0.f);
        e1[(size_t)(b0 + 1) * 512 + o] = fmaxf(a1, 0.f);
        e1[(size_t)(b0 + 2) * 512 + o] = fmaxf(a2, 0.f);
        e1[(size_t)(b0 + 3) * 512 + o] = fmaxf(a3, 0.f);
    }
}

// ---------------- Kernel C: enc2 (s2) + enc3 (s2) + enc4 fused ----------------
// grid 2048, block 256, 4 batches/block. xout layout: [b][oc], idx = b*128 + oc
__global__ __launch_bounds__(256) void k_enc234(const float* __restrict__ e1,
                                                const float* __restrict__ w2T, const float* __restrict__ b2,
                                                const float* __restrict__ w3T, const float* __restrict__ b3,
                                                const float* __restrict__ w4T, const float* __restrict__ b4,
                                                float* __restrict__ xout) {
    __shared__ float s1[4][512];
    __shared__ float s2[4][128];   // [u*64 + ch]
    __shared__ float s3[4][64];
    const int tid = threadIdx.x;
    const int b0 = blockIdx.x << 2;
    for (int i = tid; i < 4 * 512; i += 256) {
        int bl = i >> 9, jx = i & 511;
        s1[bl][jx] = e1[(size_t)(b0 + bl) * 512 + jx];
    }
    __syncthreads();
    // enc2: stride 2, pad 1, input len 4 -> output len 2
    for (int o = tid; o < 512; o += 256) {
        const int bl = o >> 7, rest = o & 127, u = rest >> 6, oc = rest & 63;
        float acc = b2[oc];
        const float* wp = w2T + oc;
        if (u == 0) {
            #pragma unroll 4
            for (int ic = 0; ic < 128; ++ic)
                acc += wp[(size_t)(ic * 3 + 1) * 64] * s1[bl][ic]
                     + wp[(size_t)(ic * 3 + 2) * 64] * s1[bl][128 + ic];
        } else {
            #pragma unroll 4
            for (int ic = 0; ic < 128; ++ic)
                acc += wp[(size_t)(ic * 3 + 0) * 64] * s1[bl][128 + ic]
                     + wp[(size_t)(ic * 3 + 1) * 64] * s1[bl][256 + ic]
                     + wp[(size_t)(ic * 3 + 2) * 64] * s1[bl][384 + ic];
        }
        s2[bl][rest] = fmaxf(acc, 0.f);
    }
    __syncthreads();
    // enc3: stride 2, pad 1, input len 2 -> len 1 (taps kk=1,2)
    {
        const int bl = tid >> 6, oc = tid & 63;
        float acc = b3[oc];
        const float* wp = w3T + oc;
        #pragma unroll 4
        for (int ic = 0; ic < 64; ++ic)
            acc += wp[(size_t)(ic * 3 + 1) * 64] * s2[bl][ic]
                 + wp[(size_t)(ic * 3 + 2) * 64] * s2[bl][64 + ic];
        s3[bl][oc] = fmaxf(acc, 0.f);
    }
    __syncthreads();
    // enc4: stride 1, pad 1, input len 1 -> len 1 (only kk=1)
    for (int o = tid; o < 512; o += 256) {
        const int bl = o >> 7, oc = o & 127;
        float acc = b4[oc];
        const float* wp = w4T + oc;
        #pragma unroll 4
        for (int ic = 0; ic < 64; ++ic)
            acc += wp[(size_t)(ic * 3 + 1) * 128] * s3[bl][ic];
        xout[(size_t)(b0 + bl) * 128 + oc] = fmaxf(acc, 0.f);
    }
}

// ---------------- Kernel D: LSTM cell + head ----------------
// grid 1024, block 256, 8 batches/block. WT[m][k*128+j], m order: wi,wf,wg,wo,ui,uf,ug,uo
__global__ __launch_bounds__(256) void k_lstm(const float* __restrict__ x,
                                              const float* __restrict__ hin, const float* __restrict__ cin,
                                              const float* __restrict__ WT,
                                              const float* __restrict__ bxi, const float* __restrict__ bxf,
                                              const float* __restrict__ bxg, const float* __restrict__ bxo,
                                              const float* __restrict__ bhi, const float* __restrict__ bhf,
                                              const float* __restrict__ bhg, const float* __restrict__ bho,
                                              const float* __restrict__ cw, const float* __restrict__ cb,
                                              float* __restrict__ out) {
    __shared__ float xsh[8][128];
    __shared__ float hsh[8][128];
    __shared__ float red[8][128];
    const int tid = threadIdx.x;
    const int b0 = blockIdx.x << 3;
    for (int i = tid; i < 8 * 128; i += 256) {
        int bl = i >> 7, jx = i & 127;
        xsh[bl][jx] = x[(size_t)(b0 + bl) * 128 + jx];
        hsh[bl][jx] = hin[(size_t)(b0 + bl) * 128 + jx];
    }
    __syncthreads();
    const int g = tid >> 7;      // 0..1: which 4-batch group
    const int j = tid & 127;     // hidden unit
    const int blb = g << 2;
    float ai[4], af[4], ag[4], ao[4];
    const float bi = bxi[j] + bhi[j];
    const float bf = bxf[j] + bhf[j];
    const float bg = bxg[j] + bhg[j];
    const float bo = bxo[j] + bho[j];
    #pragma unroll
    for (int bb = 0; bb < 4; ++bb) { ai[bb] = bi; af[bb] = bf; ag[bb] = bg; ao[bb] = bo; }
    const float* wp = WT + j;
    #pragma unroll 4
    for (int k = 0; k < 128; ++k) {
        const float w0 = wp[(size_t)k * 128];                 // wi
        const float w1 = wp[(size_t)k * 128 + 16384];         // wf
        const float w2 = wp[(size_t)k * 128 + 32768];         // wg
        const float w3 = wp[(size_t)k * 128 + 49152];         // wo
        const float u0 = wp[(size_t)k * 128 + 65536];         // ui
        const float u1 = wp[(size_t)k * 128 + 81920];         // uf
        const float u2 = wp[(size_t)k * 128 + 98304];         // ug
        const float u3 = wp[(size_t)k * 128 + 114688];        // uo
        #pragma unroll
        for (int bb = 0; bb < 4; ++bb) {
            const float xv = xsh[blb + bb][k];
            const float hv = hsh[blb + bb][k];
            ai[bb] += w0 * xv + u0 * hv;
            af[bb] += w1 * xv + u1 * hv;
            ag[bb] += w2 * xv + u2 * hv;
            ao[bb] += w3 * xv + u3 * hv;
        }
    }
    const float cwj = cw[j];
    #pragma unroll
    for (int bb = 0; bb < 4; ++bb) {
        const int b = b0 + blb + bb;
        const float ig = sigm(ai[bb]);
        const float fg = sigm(af[bb]);
        const float gg = tanhf(ag[bb]);
        const float og = sigm(ao[bb]);
        const float ci = cin[(size_t)b * 128 + j];
        const float co = fg * ci + ig * gg;
        const float ho = og * tanhf(co);
        out[(size_t)BATCH + (size_t)b * 128 + j] = ho;                         // h_out
        out[(size_t)BATCH + (size_t)BATCH * 128 + (size_t)b * 128 + j] = co;   // c_out
        red[blb + bb][j] = fmaxf(ho, 0.f) * cwj;
    }
    __syncthreads();
    if (tid < 8) {
        float s = 0.f;
        for (int k = 0; k < 128; ++k) s += red[tid][k];
        out[b0 + tid] = sigm(s + cb[0]);                                       // prob
    }
}

extern "C" void kernel_launch(void* const* d_in, const int* in_sizes, int n_in,
                              void* d_out, int out_size, void* d_ws, size_t ws_size,
                              hipStream_t stream) {
    const float* audio = (const float*)d_in[0];
    const float* hin   = (const float*)d_in[1];
    const float* cin   = (const float*)d_in[2];
    const float* fb    = (const float*)d_in[3];
    const float* w1    = (const float*)d_in[4];
    const float* b1    = (const float*)d_in[5];
    const float* w2    = (const float*)d_in[6];
    const float* b2    = (const float*)d_in[7];
    const float* w3    = (const float*)d_in[8];
    const float* b3    = (const float*)d_in[9];
    const float* w4    = (const float*)d_in[10];
    const float* b4    = (const float*)d_in[11];
    const float* wi    = (const float*)d_in[12];
    const float* wf    = (const float*)d_in[13];
    const float* wg    = (const float*)d_in[14];
    const float* wo    = (const float*)d_in[15];
    const float* ui    = (const float*)d_in[16];
    const float* uf    = (const float*)d_in[17];
    const float* ug    = (const float*)d_in[18];
    const float* uo    = (const float*)d_in[19];
    const float* bxi   = (const float*)d_in[20];
    const float* bxf   = (const float*)d_in[21];
    const float* bxg   = (const float*)d_in[22];
    const float* bxo   = (const float*)d_in[23];
    const float* bhi   = (const float*)d_in[24];
    const float* bhf   = (const float*)d_in[25];
    const float* bhg   = (const float*)d_in[26];
    const float* bho   = (const float*)d_in[27];
    const float* cw    = (const float*)d_in[28];
    const float* cb    = (const float*)d_in[29];
    float* out = (float*)d_out;

    float* ws   = (float*)d_ws;
    float* mag  = ws;                           // 8192*516
    float* e1   = mag + (size_t)BATCH * 516;    // 8192*512
    float* xbuf = e1 + (size_t)BATCH * 512;     // 8192*128
    float* fbT  = xbuf + (size_t)BATCH * 128;   // 66048
    float* w1T  = fbT + N_FBT;                  // 49536
    float* w2T  = w1T + N_W1T;                  // 24576
    float* w3T  = w2T + N_W2T;                  // 12288
    float* w4T  = w3T + N_W3T;                  // 24576
    float* WT   = w4T + N_W4T;                  // 131072

    k_prep<<<512, 256, 0, stream>>>(fb, w1, w2, w3, w4, wi, wf, wg, wo, ui, uf, ug, uo,
                                    fbT, w1T, w2T, w3T, w4T, WT);
    k_stft<<<BATCH / 4, 256, 0, stream>>>(audio, fbT, mag);
    k_enc1<<<BATCH / 4, 256, 0, stream>>>(mag, w1T, b1, e1);
    k_enc234<<<BATCH / 4, 256, 0, stream>>>(e1, w2T, b2, w3T, b3, w4T, b4, xbuf);
    k_lstm<<<BATCH / 8, 256, 0, stream>>>(xbuf, hin, cin, WT,
                                          bxi, bxf, bxg, bxo, bhi, bhf, bhg, bho,
                                          cw, cb, out);
}

// Round 4
// 334.396 us; speedup vs baseline: 2.9535x; 1.4366x over previous
//
#include <hip/hip_runtime.h>
#include <math.h>

#define BATCH 8192
typedef unsigned short u16;
typedef unsigned int u32;
typedef __attribute__((ext_vector_type(8))) short bf16x8;
typedef __attribute__((ext_vector_type(4))) float f32x4;
typedef __attribute__((ext_vector_type(4))) unsigned short u16x4;

__device__ __forceinline__ float sigm(float v) { return 1.0f / (1.0f + __expf(-v)); }
__device__ __forceinline__ u16 f2bf(float f) {
    union { float f; u32 u; } v; v.f = f;
    u32 r = v.u + 0x7FFFu + ((v.u >> 16) & 1u);   // RNE
    return (u16)(r >> 16);
}
__device__ __forceinline__ float bf2f(u16 h) {
    union { u32 u; float f; } v; v.u = ((u32)h) << 16; return v.f;
}
__device__ __forceinline__ void split_store4(float4 v, u16* hp, u16* lp) {
    u16 h0 = f2bf(v.x), h1 = f2bf(v.y), h2 = f2bf(v.z), h3 = f2bf(v.w);
    u16x4 hv = {h0, h1, h2, h3};
    u16x4 lv = {f2bf(v.x - bf2f(h0)), f2bf(v.y - bf2f(h1)),
                f2bf(v.z - bf2f(h2)), f2bf(v.w - bf2f(h3))};
    *(u16x4*)hp = hv; *(u16x4*)lp = lv;
}

// ---------------- workspace layout ----------------
// Each weight matrix: hi plane then lo plane (u16 each, S elements/plane).
#define S_FBT 69632   // [272][256]
#define S_B1  61440   // [3][128][160]
#define S_B2A 16384   // [64][256]
#define S_B2B 24576   // [64][384]
#define S_B3  8192    // [64][128]
#define S_B4  8192    // [128][64]
#define S_BL  131072  // [512][256]
#define P_FBT 0
#define P_B1  139264
#define P_B2A 262144
#define P_B2B 294912
#define P_B3  344064
#define P_B4  360448
#define P_BL  376832
#define WEND  638976
#define N_PREP 319488
// ACT: fp32 [8192][640] after weights. Row usage over time:
//   stft: [0..639]=mag(4x160) ; enc1: reads mag, writes e1 [0..511]
//   enc2a: reads [0..255] -> writes [512..575]; enc2b: reads [128..511] -> [576..639]
//   enc3: reads [512..639] -> [0..63]; enc4: reads [0..63] -> x [64..191]
//   lstm: reads x=[64..191] + hin.

// ---------------- k_prep: split all weights into bf16 hi/lo planes ----------------
__global__ __launch_bounds__(256) void k_prep(const float* __restrict__ fb,
                                              const float* __restrict__ w1, const float* __restrict__ w2,
                                              const float* __restrict__ w3, const float* __restrict__ w4,
                                              const float* __restrict__ wi, const float* __restrict__ wf,
                                              const float* __restrict__ wg, const float* __restrict__ wo,
                                              const float* __restrict__ ui, const float* __restrict__ uf,
                                              const float* __restrict__ ug, const float* __restrict__ uo,
                                              u16* __restrict__ wsu) {
    const float* Ws[8] = {wi, wf, wg, wo, ui, uf, ug, uo};
    for (int i = blockIdx.x * 256 + threadIdx.x; i < N_PREP; i += gridDim.x * 256) {
        int r = i;
        float v; int P, S, idx;
        if (r < S_FBT) {
            int n = r >> 8, k = r & 255, c = n >> 1, part = n & 1;
            v = (n < 258) ? fb[(size_t)(c + part * 129) * 256 + k] : 0.f;
            P = P_FBT; S = S_FBT; idx = r;
        } else if ((r -= S_FBT) < S_B1) {
            int kk = r / 20480, rem = r - kk * 20480;
            int oc = rem / 160, cc = rem - oc * 160;
            v = (cc < 129) ? w1[(size_t)oc * 387 + cc * 3 + kk] : 0.f;
            P = P_B1; S = S_B1; idx = r;
        } else if ((r -= S_B1) < S_B2A) {
            int oc = r >> 8, rem = r & 255, tt = rem >> 7, ic = rem & 127;
            v = w2[(size_t)oc * 384 + ic * 3 + tt + 1];
            P = P_B2A; S = S_B2A; idx = r;
        } else if ((r -= S_B2A) < S_B2B) {
            int oc = r / 384, rem = r - oc * 384, q = rem >> 7, ic = rem & 127;
            v = w2[(size_t)oc * 384 + ic * 3 + q];
            P = P_B2B; S = S_B2B; idx = r;
        } else if ((r -= S_B2B) < S_B3) {
            int oc = r >> 7, rem = r & 127, u = rem >> 6, ch = rem & 63;
            v = w3[(size_t)oc * 192 + ch * 3 + u + 1];
            P = P_B3; S = S_B3; idx = r;
        } else if ((r -= S_B3) < S_B4) {
            int oc = r >> 6, ch = r & 63;
            v = w4[(size_t)oc * 192 + ch * 3 + 1];
            P = P_B4; S = S_B4; idx = r;
        } else {
            r -= S_B4;
            int n = r >> 8, k = r & 255, g = n >> 7, j = n & 127;
            v = Ws[g + ((k >= 128) ? 4 : 0)][(size_t)j * 128 + (k & 127)];
            P = P_BL; S = S_BL; idx = r;
        }
        u16 h = f2bf(v);
        wsu[P + idx] = h;
        wsu[P + S + idx] = f2bf(v - bf2f(h));
    }
}

#define MFMA(a, b, c) __builtin_amdgcn_mfma_f32_16x16x32_bf16(a, b, c, 0, 0, 0)

// ---------------- k_stft: split GEMM M=32768 K=256 N=272 + |.| epilogue ----------------
// block 256 (4 waves), 16 batches (64 rows), grid 512
__global__ __launch_bounds__(256) void k_stft(const float* __restrict__ audio,
                                              const u16* __restrict__ fbT,
                                              float* __restrict__ act) {
    __shared__ __align__(16) u16 sAh[16 * 640];
    __shared__ __align__(16) u16 sAl[16 * 640];
    __shared__ __align__(16) u16 sBh[144 * 32];
    __shared__ __align__(16) u16 sBl[144 * 32];
    const int tid = threadIdx.x;
    const int b0 = blockIdx.x << 4;
    for (int i = tid; i < 16 * 640; i += 256) {
        int bb = i / 640, j = i - bb * 640;
        int jj = (j < 576) ? j : (1150 - j);            // reflect pad
        float v = audio[(size_t)(b0 + bb) * 576 + jj];
        u16 h = f2bf(v);
        sAh[i] = h; sAl[i] = f2bf(v - bf2f(h));
    }
    const int lane = tid & 63, wid = tid >> 6;
    const int m = lane & 15, quad = lane >> 4;
    const int Rm = wid * 16 + m;
    const int abase = (Rm >> 2) * 640 + (Rm & 3) * 128 + quad * 8;
    f32x4 acc[17];
    #pragma unroll
    for (int t = 0; t < 17; ++t) acc[t] = (f32x4){0.f, 0.f, 0.f, 0.f};
    for (int ch = 0; ch < 8; ++ch) {
        __syncthreads();
        for (int i = tid; i < 144 * 4; i += 256) {
            int n = i >> 2, p = i & 3;
            *(uint4*)(sBh + n * 32 + p * 8) = *(const uint4*)(fbT + (size_t)n * 256 + ch * 32 + p * 8);
            *(uint4*)(sBl + n * 32 + p * 8) = *(const uint4*)(fbT + S_FBT + (size_t)n * 256 + ch * 32 + p * 8);
        }
        __syncthreads();
        bf16x8 vah = *(const bf16x8*)(sAh + abase + ch * 32);
        bf16x8 val = *(const bf16x8*)(sAl + abase + ch * 32);
        #pragma unroll
        for (int t = 0; t < 9; ++t) {
            bf16x8 vbh = *(const bf16x8*)(sBh + (t * 16 + m) * 32 + quad * 8);
            bf16x8 vbl = *(const bf16x8*)(sBl + (t * 16 + m) * 32 + quad * 8);
            acc[t] = MFMA(vah, vbh, acc[t]);
            acc[t] = MFMA(vah, vbl, acc[t]);
            acc[t] = MFMA(val, vbh, acc[t]);
        }
        __syncthreads();
        for (int i = tid; i < 128 * 4; i += 256) {
            int n = i >> 2, p = i & 3;
            *(uint4*)(sBh + n * 32 + p * 8) = *(const uint4*)(fbT + (size_t)(144 + n) * 256 + ch * 32 + p * 8);
            *(uint4*)(sBl + n * 32 + p * 8) = *(const uint4*)(fbT + S_FBT + (size_t)(144 + n) * 256 + ch * 32 + p * 8);
        }
        __syncthreads();
        #pragma unroll
        for (int t = 9; t < 17; ++t) {
            bf16x8 vbh = *(const bf16x8*)(sBh + (t * 16 + m - 144) * 32 + quad * 8);
            bf16x8 vbl = *(const bf16x8*)(sBl + (t * 16 + m - 144) * 32 + quad * 8);
            acc[t] = MFMA(vah, vbh, acc[t]);
            acc[t] = MFMA(vah, vbl, acc[t]);
            acc[t] = MFMA(val, vbh, acc[t]);
        }
    }
    const int R2 = wid * 16 + quad * 4;
    #pragma unroll
    for (int t = 0; t < 17; ++t) {
        const int n = t * 16 + m;
        #pragma unroll
        for (int r = 0; r < 4; ++r) {
            float v = acc[t][r];
            float s = v * v;
            s += __shfl_xor(s, 1);
            if (!(n & 1)) {
                int R = R2 + r;
                act[(size_t)(b0 + (R >> 2)) * 640 + (R & 3) * 160 + (n >> 1)] = sqrtf(s);
            }
        }
    }
    for (int i = tid; i < 16 * 4 * 24; i += 256) {      // zero pad c=136..159
        int r = i / 24, c = 136 + i - (i / 24) * 24;
        act[(size_t)(b0 + (r >> 2)) * 640 + (r & 3) * 160 + c] = 0.f;
    }
}

// ---------------- k_enc1: 3-tap accumulated split GEMM, K=160/tap, N=128 ----------------
// block 128 (2 waves), 8 batches (32 rows), grid 1024
__global__ __launch_bounds__(128) void k_enc1(float* __restrict__ act,
                                              const u16* __restrict__ B1w,
                                              const float* __restrict__ b1) {
    __shared__ __align__(16) u16 sAh[8 * 6 * 160];
    __shared__ __align__(16) u16 sAl[8 * 6 * 160];
    __shared__ __align__(16) u16 sBh[128 * 32];
    __shared__ __align__(16) u16 sBl[128 * 32];
    const int tid = threadIdx.x;
    const int b0 = blockIdx.x << 3;
    for (int i = tid; i < 8 * 6 * 160; i += 128) {
        int bb = i / 960, rem = i - bb * 960;
        int tp = rem / 160, cc = rem - tp * 160;
        float v = (tp >= 1 && tp <= 4) ? act[(size_t)(b0 + bb) * 640 + (tp - 1) * 160 + cc] : 0.f;
        u16 h = f2bf(v);
        sAh[i] = h; sAl[i] = f2bf(v - bf2f(h));
    }
    const int lane = tid & 63, wid = tid >> 6;    // wid 0..1
    const int m = lane & 15, quad = lane >> 4;
    const int Rm = wid * 16 + m;                  // 0..31
    const int bl_a = Rm >> 2, t_a = Rm & 3;
    f32x4 acc[8];
    #pragma unroll
    for (int t = 0; t < 8; ++t) acc[t] = (f32x4){0.f, 0.f, 0.f, 0.f};
    for (int kk = 0; kk < 3; ++kk) {
        const int arow = (bl_a * 6 + t_a + kk) * 160;
        for (int ch = 0; ch < 5; ++ch) {
            __syncthreads();
            for (int i = tid; i < 128 * 4; i += 128) {
                int n = i >> 2, p = i & 3;
                *(uint4*)(sBh + n * 32 + p * 8) =
                    *(const uint4*)(B1w + (size_t)kk * 20480 + (size_t)n * 160 + ch * 32 + p * 8);
                *(uint4*)(sBl + n * 32 + p * 8) =
                    *(const uint4*)(B1w + S_B1 + (size_t)kk * 20480 + (size_t)n * 160 + ch * 32 + p * 8);
            }
            __syncthreads();
            bf16x8 vah = *(const bf16x8*)(sAh + arow + ch * 32 + quad * 8);
            bf16x8 val = *(const bf16x8*)(sAl + arow + ch * 32 + quad * 8);
            #pragma unroll
            for (int t = 0; t < 8; ++t) {
                bf16x8 vbh = *(const bf16x8*)(sBh + (t * 16 + m) * 32 + quad * 8);
                bf16x8 vbl = *(const bf16x8*)(sBl + (t * 16 + m) * 32 + quad * 8);
                acc[t] = MFMA(vah, vbh, acc[t]);
                acc[t] = MFMA(vah, vbl, acc[t]);
                acc[t] = MFMA(val, vbh, acc[t]);
            }
        }
    }
    const int R2 = wid * 16 + quad * 4;
    #pragma unroll
    for (int t = 0; t < 8; ++t) {
        const int n = t * 16 + m;
        const float bv = b1[n];
        #pragma unroll
        for (int r = 0; r < 4; ++r) {
            int R = R2 + r;
            act[(size_t)(b0 + (R >> 2)) * 640 + (R & 3) * 128 + n] = fmaxf(acc[t][r] + bv, 0.f);
        }
    }
}

// ---------------- k_gemm: generic relu(A_win*B + bias) split GEMM, BM=32, block 128 ----------------
__global__ __launch_bounds__(128) void k_gemm(float* __restrict__ act, int awoff, int K,
                                              const u16* __restrict__ Bm, int bsz, int N,
                                              const float* __restrict__ bias, int ooff) {
    __shared__ __align__(16) u16 sAh[32 * 384];
    __shared__ __align__(16) u16 sAl[32 * 384];
    __shared__ __align__(16) u16 sBh[64 * 32];
    __shared__ __align__(16) u16 sBl[64 * 32];
    const int tid = threadIdx.x;
    const int b0 = blockIdx.x << 5;
    const int kd4 = K >> 2;
    for (int i = tid; i < 32 * kd4; i += 128) {
        int r = i / kd4, p = i - r * kd4;
        float4 v = *(const float4*)(act + (size_t)(b0 + r) * 640 + awoff + p * 4);
        split_store4(v, sAh + r * K + p * 4, sAl + r * K + p * 4);
    }
    const int lane = tid & 63, wid = tid >> 6;
    const int m = lane & 15, quad = lane >> 4;
    const int nt = N >> 4, nch = K >> 5, nsub = (nt + 3) >> 2;
    f32x4 acc[8];
    #pragma unroll
    for (int t = 0; t < 8; ++t) acc[t] = (f32x4){0.f, 0.f, 0.f, 0.f};
    const int arow = (wid * 16 + m) * K;
    for (int ch = 0; ch < nch; ++ch) {
        for (int s = 0; s < nsub; ++s) {
            __syncthreads();
            const int nbase = s * 64;
            const int rows = ((N - nbase) < 64) ? (N - nbase) : 64;
            for (int i = tid; i < rows * 4; i += 128) {
                int n = i >> 2, p = i & 3;
                *(uint4*)(sBh + n * 32 + p * 8) = *(const uint4*)(Bm + (size_t)(nbase + n) * K + ch * 32 + p * 8);
                *(uint4*)(sBl + n * 32 + p * 8) = *(const uint4*)(Bm + bsz + (size_t)(nbase + n) * K + ch * 32 + p * 8);
            }
            __syncthreads();
            bf16x8 vah = *(const bf16x8*)(sAh + arow + ch * 32 + quad * 8);
            bf16x8 val = *(const bf16x8*)(sAl + arow + ch * 32 + quad * 8);
            const int tend = ((s + 1) * 4 < nt) ? (s + 1) * 4 : nt;
            for (int t = s * 4; t < tend; ++t) {
                bf16x8 vbh = *(const bf16x8*)(sBh + ((t * 16 - nbase) + m) * 32 + quad * 8);
                bf16x8 vbl = *(const bf16x8*)(sBl + ((t * 16 - nbase) + m) * 32 + quad * 8);
                acc[t] = MFMA(vah, vbh, acc[t]);
                acc[t] = MFMA(vah, vbl, acc[t]);
                acc[t] = MFMA(val, vbh, acc[t]);
            }
        }
    }
    const int row = wid * 16 + quad * 4;
    for (int t = 0; t < nt; ++t) {
        const int n = t * 16 + m;
        const float bv = bias[n];
        #pragma unroll
        for (int r = 0; r < 4; ++r)
            act[(size_t)(b0 + row + r) * 640 + ooff + n] = fmaxf(acc[t][r] + bv, 0.f);
    }
}

// ---------------- k_lstm: split GEMM M=8192 K=256 N=512 + fused cell/head ----------------
// block 256 (4 waves): 2 row-groups x 2 j-halves; BM=32; grid 256
__global__ __launch_bounds__(256) void k_lstm(const float* __restrict__ act, const float* __restrict__ hin,
                                              const u16* __restrict__ BL,
                                              const float* __restrict__ cin,
                                              const float* __restrict__ bxi, const float* __restrict__ bxf,
                                              const float* __restrict__ bxg, const float* __restrict__ bxo,
                                              const float* __restrict__ bhi, const float* __restrict__ bhf,
                                              const float* __restrict__ bhg, const float* __restrict__ bho,
                                              const float* __restrict__ cw, const float* __restrict__ cb,
                                              float* __restrict__ out) {
    __shared__ __align__(16) u16 sAh[32 * 256];
    __shared__ __align__(16) u16 sAl[32 * 256];
    __shared__ __align__(16) u16 sBh[128 * 32];
    __shared__ __align__(16) u16 sBl[128 * 32];
    __shared__ float pr[2][32];
    const int tid = threadIdx.x;
    const int b0 = blockIdx.x << 5;
    for (int i = tid; i < 32 * 64; i += 256) {
        int r = i >> 6, p = i & 63;
        int k0 = p * 4;
        float4 v = (k0 < 128) ? *(const float4*)(act + (size_t)(b0 + r) * 640 + 64 + k0)
                              : *(const float4*)(hin + (size_t)(b0 + r) * 128 + (k0 - 128));
        split_store4(v, sAh + r * 256 + k0, sAl + r * 256 + k0);
    }
    const int lane = tid & 63, wid = tid >> 6;
    const int m = lane & 15, quad = lane >> 4;
    const int jh = wid & 1, rg = wid >> 1;
    f32x4 acc[16];
    #pragma unroll
    for (int t = 0; t < 16; ++t) acc[t] = (f32x4){0.f, 0.f, 0.f, 0.f};
    const int arow = (rg * 16 + m) * 256;
    for (int ch = 0; ch < 8; ++ch) {
        for (int g = 0; g < 4; ++g) {
            __syncthreads();
            for (int i = tid; i < 128 * 4; i += 256) {
                int n = i >> 2, p = i & 3;
                *(uint4*)(sBh + n * 32 + p * 8) = *(const uint4*)(BL + (size_t)(g * 128 + n) * 256 + ch * 32 + p * 8);
                *(uint4*)(sBl + n * 32 + p * 8) = *(const uint4*)(BL + S_BL + (size_t)(g * 128 + n) * 256 + ch * 32 + p * 8);
            }
            __syncthreads();
            bf16x8 vah = *(const bf16x8*)(sAh + arow + ch * 32 + quad * 8);
            bf16x8 val = *(const bf16x8*)(sAl + arow + ch * 32 + quad * 8);
            #pragma unroll
            for (int jj = 0; jj < 4; ++jj) {
                const int nl = (jh * 4 + jj) * 16 + m;
                bf16x8 vbh = *(const bf16x8*)(sBh + nl * 32 + quad * 8);
                bf16x8 vbl = *(const bf16x8*)(sBl + nl * 32 + quad * 8);
                acc[g * 4 + jj] = MFMA(vah, vbh, acc[g * 4 + jj]);
                acc[g * 4 + jj] = MFMA(vah, vbl, acc[g * 4 + jj]);
                acc[g * 4 + jj] = MFMA(val, vbh, acc[g * 4 + jj]);
            }
        }
    }
    float partial[4] = {0.f, 0.f, 0.f, 0.f};
    #pragma unroll
    for (int jj = 0; jj < 4; ++jj) {
        const int j = (jh * 4 + jj) * 16 + m;
        const float bi = bxi[j] + bhi[j];
        const float bff = bxf[j] + bhf[j];
        const float bgg = bxg[j] + bhg[j];
        const float boo = bxo[j] + bho[j];
        const float cwj = cw[j];
        #pragma unroll
        for (int r = 0; r < 4; ++r) {
            const int b = b0 + rg * 16 + quad * 4 + r;
            const float ig = sigm(acc[0 * 4 + jj][r] + bi);
            const float fg = sigm(acc[1 * 4 + jj][r] + bff);
            const float gg = tanhf(acc[2 * 4 + jj][r] + bgg);
            const float og = sigm(acc[3 * 4 + jj][r] + boo);
            const float ci = cin[(size_t)b * 128 + j];
            const float co = fg * ci + ig * gg;
            const float ho = og * tanhf(co);
            out[(size_t)BATCH + (size_t)b * 128 + j] = ho;
            out[(size_t)BATCH + (size_t)BATCH * 128 + (size_t)b * 128 + j] = co;
            partial[r] += fmaxf(ho, 0.f) * cwj;
        }
    }
    #pragma unroll
    for (int off = 1; off < 16; off <<= 1)
        #pragma unroll
        for (int r = 0; r < 4; ++r) partial[r] += __shfl_xor(partial[r], off);
    if (m == 0) {
        #pragma unroll
        for (int r = 0; r < 4; ++r) pr[jh][rg * 16 + quad * 4 + r] = partial[r];
    }
    __syncthreads();
    if (tid < 32) out[b0 + tid] = sigm(pr[0][tid] + pr[1][tid] + cb[0]);
}

extern "C" void kernel_launch(void* const* d_in, const int* in_sizes, int n_in,
                              void* d_out, int out_size, void* d_ws, size_t ws_size,
                              hipStream_t stream) {
    const float* audio = (const float*)d_in[0];
    const float* hin   = (const float*)d_in[1];
    const float* cin   = (const float*)d_in[2];
    const float* fb    = (const float*)d_in[3];
    const float* w1    = (const float*)d_in[4];
    const float* b1    = (const float*)d_in[5];
    const float* w2    = (const float*)d_in[6];
    const float* b2    = (const float*)d_in[7];
    const float* w3    = (const float*)d_in[8];
    const float* b3    = (const float*)d_in[9];
    const float* w4    = (const float*)d_in[10];
    const float* b4    = (const float*)d_in[11];
    const float* wi    = (const float*)d_in[12];
    const float* wf    = (const float*)d_in[13];
    const float* wg    = (const float*)d_in[14];
    const float* wo    = (const float*)d_in[15];
    const float* ui    = (const float*)d_in[16];
    const float* uf    = (const float*)d_in[17];
    const float* ug    = (const float*)d_in[18];
    const float* uo    = (const float*)d_in[19];
    const float* bxi   = (const float*)d_in[20];
    const float* bxf   = (const float*)d_in[21];
    const float* bxg   = (const float*)d_in[22];
    const float* bxo   = (const float*)d_in[23];
    const float* bhi   = (const float*)d_in[24];
    const float* bhf   = (const float*)d_in[25];
    const float* bhg   = (const float*)d_in[26];
    const float* bho   = (const float*)d_in[27];
    const float* cw    = (const float*)d_in[28];
    const float* cb    = (const float*)d_in[29];
    float* out = (float*)d_out;

    u16* wsu = (u16*)d_ws;
    float* ACT = (float*)(wsu + WEND);           // [8192][640] fp32

    k_prep<<<640, 256, 0, stream>>>(fb, w1, w2, w3, w4, wi, wf, wg, wo, ui, uf, ug, uo, wsu);
    k_stft<<<BATCH / 16, 256, 0, stream>>>(audio, wsu + P_FBT, ACT);
    k_enc1<<<BATCH / 8, 128, 0, stream>>>(ACT, wsu + P_B1, b1);
    k_gemm<<<BATCH / 32, 128, 0, stream>>>(ACT, 0,   256, wsu + P_B2A, S_B2A, 64,  b2, 512);
    k_gemm<<<BATCH / 32, 128, 0, stream>>>(ACT, 128, 384, wsu + P_B2B, S_B2B, 64,  b2, 576);
    k_gemm<<<BATCH / 32, 128, 0, stream>>>(ACT, 512, 128, wsu + P_B3,  S_B3,  64,  b3, 0);
    k_gemm<<<BATCH / 32, 128, 0, stream>>>(ACT, 0,   64,  wsu + P_B4,  S_B4,  128, b4, 64);
    k_lstm<<<BATCH / 32, 256, 0, stream>>>(ACT, hin, wsu + P_BL, cin,
                                           bxi, bxf, bxg, bxo, bhi, bhf, bhg, bho,
                                           cw, cb, out);
}

// Round 5
// 254.575 us; speedup vs baseline: 3.8795x; 1.3135x over previous
//
#include <hip/hip_runtime.h>
#include <math.h>

#define BATCH 8192
typedef unsigned short u16;
typedef unsigned int u32;
typedef __attribute__((ext_vector_type(8))) short bf16x8;
typedef __attribute__((ext_vector_type(4))) float f32x4;
typedef __attribute__((ext_vector_type(4))) unsigned short u16x4;

__device__ __forceinline__ float sigm(float v) { return 1.0f / (1.0f + __expf(-v)); }
__device__ __forceinline__ u16 f2bf(float f) {
    union { float f; u32 u; } v; v.f = f;
    u32 r = v.u + 0x7FFFu + ((v.u >> 16) & 1u);   // RNE
    return (u16)(r >> 16);
}
__device__ __forceinline__ float bf2f(u16 h) {
    union { u32 u; float f; } v; v.u = ((u32)h) << 16; return v.f;
}
__device__ __forceinline__ void split_store4(float4 v, u16* hp, u16* lp) {
    u16 h0 = f2bf(v.x), h1 = f2bf(v.y), h2 = f2bf(v.z), h3 = f2bf(v.w);
    u16x4 hv = {h0, h1, h2, h3};
    u16x4 lv = {f2bf(v.x - bf2f(h0)), f2bf(v.y - bf2f(h1)),
                f2bf(v.z - bf2f(h2)), f2bf(v.w - bf2f(h3))};
    *(u16x4*)hp = hv; *(u16x4*)lp = lv;
}
// fragment-linear B: element [(nt*nch + ch)*64 + lane]*8 + e  ==  B[nt*16+(lane&15)][ch*32+(lane>>4)*8+e]
__device__ __forceinline__ bf16x8 bfrag(const u16* Bf, int nt, int ch, int nch, int lane) {
    return *(const bf16x8*)(Bf + (((size_t)nt * nch + ch) * 64 + lane) * 8);
}
#define MFMA(a, b, c) __builtin_amdgcn_mfma_f32_16x16x32_bf16(a, b, c, 0, 0, 0)

// ---------------- workspace layout (u16 elements); hi plane then lo plane ----------------
#define S_FBT 69632   // [17 nt][8 ch] frag-linear, n<272, k<256
#define S_B1  61440   // 3 taps x [8 nt][5 ch], n<128, k<160
#define S_B2A 16384   // [4 nt][8 ch]
#define S_B2B 24576   // [4 nt][12 ch]
#define S_B3  8192    // [4 nt][4 ch]
#define S_B4  8192    // [8 nt][2 ch]
#define S_BL  131072  // [32 nt][8 ch]  n = gate*128+j, k: 0..127 W / 128..255 U
#define P_FBT 0
#define P_B1  139264
#define P_B2A 262144
#define P_B2B 294912
#define P_B3  344064
#define P_B4  360448
#define P_BL  376832
#define WEND  638976
#define N_PREP 319488
// ACT fp32 [8192][640]: stft->mag(4x160); enc1->e1[0..511]; enc2->[512..639];
// enc3->[0..63]; enc4->x[64..191]; lstm reads x + hin.

// ---------------- k_prep: build fragment-linear split-bf16 B planes ----------------
__global__ __launch_bounds__(256) void k_prep(const float* __restrict__ fb,
                                              const float* __restrict__ w1, const float* __restrict__ w2,
                                              const float* __restrict__ w3, const float* __restrict__ w4,
                                              const float* __restrict__ wi, const float* __restrict__ wf,
                                              const float* __restrict__ wg, const float* __restrict__ wo,
                                              const float* __restrict__ ui, const float* __restrict__ uf,
                                              const float* __restrict__ ug, const float* __restrict__ uo,
                                              u16* __restrict__ wsu) {
    const float* Ws[8] = {wi, wf, wg, wo, ui, uf, ug, uo};
    for (int i = blockIdx.x * 256 + threadIdx.x; i < N_PREP; i += gridDim.x * 256) {
        int r = i;
        float v; int P, S, idx;
        if (r < S_FBT) {                                    // FBT nch=8
            int f = r >> 9, lane = (r & 511) >> 3, e = r & 7;
            int n = (f >> 3) * 16 + (lane & 15), k = (f & 7) * 32 + (lane >> 4) * 8 + e;
            int c = n >> 1, part = n & 1;
            v = (n < 258) ? fb[(size_t)(c + part * 129) * 256 + k] : 0.f;
            P = P_FBT; S = S_FBT; idx = r;
        } else if ((r -= S_FBT) < S_B1) {                   // B1: 3 taps, nch=5
            int kk = r / 20480, r2 = r - kk * 20480;
            int f = r2 >> 9, lane = (r2 & 511) >> 3, e = r2 & 7;
            int n = (f / 5) * 16 + (lane & 15), k = (f % 5) * 32 + (lane >> 4) * 8 + e;
            v = (k < 129) ? w1[(size_t)n * 387 + k * 3 + kk] : 0.f;
            P = P_B1; S = S_B1; idx = r;
        } else if ((r -= S_B1) < S_B2A) {                   // B2A nch=8
            int f = r >> 9, lane = (r & 511) >> 3, e = r & 7;
            int n = (f >> 3) * 16 + (lane & 15), k = (f & 7) * 32 + (lane >> 4) * 8 + e;
            v = w2[(size_t)n * 384 + (k & 127) * 3 + (k >> 7) + 1];
            P = P_B2A; S = S_B2A; idx = r;
        } else if ((r -= S_B2A) < S_B2B) {                  // B2B nch=12
            int f = r >> 9, lane = (r & 511) >> 3, e = r & 7;
            int n = (f / 12) * 16 + (lane & 15), k = (f % 12) * 32 + (lane >> 4) * 8 + e;
            v = w2[(size_t)n * 384 + (k & 127) * 3 + (k >> 7)];
            P = P_B2B; S = S_B2B; idx = r;
        } else if ((r -= S_B2B) < S_B3) {                   // B3 nch=4
            int f = r >> 9, lane = (r & 511) >> 3, e = r & 7;
            int n = (f >> 2) * 16 + (lane & 15), k = (f & 3) * 32 + (lane >> 4) * 8 + e;
            v = w3[(size_t)n * 192 + (k & 63) * 3 + (k >> 6) + 1];
            P = P_B3; S = S_B3; idx = r;
        } else if ((r -= S_B3) < S_B4) {                    // B4 nch=2
            int f = r >> 9, lane = (r & 511) >> 3, e = r & 7;
            int n = (f >> 1) * 16 + (lane & 15), k = (f & 1) * 32 + (lane >> 4) * 8 + e;
            v = w4[(size_t)n * 192 + k * 3 + 1];
            P = P_B4; S = S_B4; idx = r;
        } else {                                            // BL nch=8
            r -= S_B4;
            int f = r >> 9, lane = (r & 511) >> 3, e = r & 7;
            int n = (f >> 3) * 16 + (lane & 15), k = (f & 7) * 32 + (lane >> 4) * 8 + e;
            int g = n >> 7, j = n & 127;
            v = Ws[g + ((k >= 128) ? 4 : 0)][(size_t)j * 128 + (k & 127)];
            P = P_BL; S = S_BL; idx = r;
        }
        u16 h = f2bf(v);
        wsu[P + idx] = h;
        wsu[P + S + idx] = f2bf(v - bf2f(h));
    }
}

// ---------------- k_stft: split GEMM M=32768 K=256 N=272, barrier-free K-loop ----------------
// block 256 (4 waves: rg x nh), 16 batches (64 rows), grid 512
// A LDS layout: per batch 680 u16, phys = bl*680 + pos + (pos>>7)*8  (pos = t*128+k)
__global__ __launch_bounds__(256) void k_stft(const float* __restrict__ audio,
                                              const u16* __restrict__ fbT,
                                              float* __restrict__ act) {
    __shared__ __align__(16) u16 sAh[16 * 680];
    __shared__ __align__(16) u16 sAl[16 * 680];
    const int tid = threadIdx.x;
    const int b0 = blockIdx.x << 4;
    for (int i = tid; i < 16 * 4 * 24; i += 256) {          // zero mag cols 136..159
        int rr = i / 24, c = 136 + (i - rr * 24);
        act[(size_t)(b0 + (rr >> 2)) * 640 + (rr & 3) * 160 + c] = 0.f;
    }
    for (int i = tid; i < 16 * 160; i += 256) {
        int bb = i / 160, j4 = (i - bb * 160) * 4;
        const float* ap = audio + (size_t)(b0 + bb) * 576;
        float4 v;
        if (j4 < 576) v = *(const float4*)(ap + j4);
        else { v.x = ap[1150 - j4]; v.y = ap[1149 - j4]; v.z = ap[1148 - j4]; v.w = ap[1147 - j4]; }
        int phys = bb * 680 + j4 + (j4 >> 7) * 8;
        split_store4(v, sAh + phys, sAl + phys);
    }
    __syncthreads();
    const int lane = tid & 63, w = tid >> 6;
    const int m = lane & 15, quad = lane >> 4;
    const int rg = w & 1, nh = w >> 1;
    const int tbase = nh * 9;
    f32x4 acc[2][9];
    #pragma unroll
    for (int mt = 0; mt < 2; ++mt)
        #pragma unroll
        for (int t = 0; t < 9; ++t) acc[mt][t] = (f32x4){0.f, 0.f, 0.f, 0.f};
    for (int ch = 0; ch < 8; ++ch) {
        bf16x8 ah[2], al[2];
        #pragma unroll
        for (int mt = 0; mt < 2; ++mt) {
            int Rm = rg * 32 + mt * 16 + m;
            int phys = (Rm >> 2) * 680 + (Rm & 3) * 136 + ch * 32 + quad * 8 + ((ch >= 4) ? 8 : 0);
            ah[mt] = *(const bf16x8*)(sAh + phys);
            al[mt] = *(const bf16x8*)(sAl + phys);
        }
        #pragma unroll
        for (int tt = 0; tt < 9; ++tt) {
            int t = tbase + tt;
            if (t < 17) {
                bf16x8 bh = bfrag(fbT, t, ch, 8, lane);
                bf16x8 bl_ = bfrag(fbT + S_FBT, t, ch, 8, lane);
                #pragma unroll
                for (int mt = 0; mt < 2; ++mt) {
                    acc[mt][tt] = MFMA(ah[mt], bh, acc[mt][tt]);
                    acc[mt][tt] = MFMA(ah[mt], bl_, acc[mt][tt]);
                    acc[mt][tt] = MFMA(al[mt], bh, acc[mt][tt]);
                }
            }
        }
    }
    #pragma unroll
    for (int tt = 0; tt < 9; ++tt) {
        int t = tbase + tt;
        if (t < 17) {
            int n = t * 16 + m;
            #pragma unroll
            for (int mt = 0; mt < 2; ++mt)
                #pragma unroll
                for (int r = 0; r < 4; ++r) {
                    float vv = acc[mt][tt][r];
                    float s = vv * vv;
                    s += __shfl_xor(s, 1);
                    if (!(n & 1)) {
                        int R = rg * 32 + mt * 16 + quad * 4 + r;
                        act[(size_t)(b0 + (R >> 2)) * 640 + (R & 3) * 160 + (n >> 1)] = sqrtf(s);
                    }
                }
        }
    }
}

// ---------------- k_enc1: 3-tap split GEMM, barrier-free K-loop ----------------
// block 256 (4 waves, N split 4x2 tiles), 16 batches (64 rows, MT=4), grid 512
// A LDS: rows (bl*6 + tp), stride 168
__global__ __launch_bounds__(256) void k_enc1(float* __restrict__ act,
                                              const u16* __restrict__ B1w,
                                              const float* __restrict__ b1) {
    __shared__ __align__(16) u16 sAh[16 * 6 * 168];
    __shared__ __align__(16) u16 sAl[16 * 6 * 168];
    const int tid = threadIdx.x;
    const int b0 = blockIdx.x << 4;
    for (int i = tid; i < 16 * 6 * 40; i += 256) {
        int bb = i / 240, rem = i - bb * 240;
        int tp = rem / 40, c4 = (rem - tp * 40) * 4;
        float4 v = {0.f, 0.f, 0.f, 0.f};
        if (tp >= 1 && tp <= 4)
            v = *(const float4*)(act + (size_t)(b0 + bb) * 640 + (tp - 1) * 160 + c4);
        int phys = (bb * 6 + tp) * 168 + c4;
        split_store4(v, sAh + phys, sAl + phys);
    }
    __syncthreads();
    const int lane = tid & 63, w = tid >> 6;
    const int m = lane & 15, quad = lane >> 4;
    f32x4 acc[4][2];
    #pragma unroll
    for (int mt = 0; mt < 4; ++mt) { acc[mt][0] = (f32x4){0,0,0,0}; acc[mt][1] = (f32x4){0,0,0,0}; }
    for (int kk = 0; kk < 3; ++kk) {
        const u16* Bh = B1w + kk * 20480;
        const u16* Bl = B1w + S_B1 + kk * 20480;
        for (int ch = 0; ch < 5; ++ch) {
            bf16x8 bh[2], bl_[2];
            #pragma unroll
            for (int q2 = 0; q2 < 2; ++q2) {
                bh[q2] = bfrag(Bh, w * 2 + q2, ch, 5, lane);
                bl_[q2] = bfrag(Bl, w * 2 + q2, ch, 5, lane);
            }
            #pragma unroll
            for (int mt = 0; mt < 4; ++mt) {
                int Rm = mt * 16 + m;
                int phys = ((Rm >> 2) * 6 + (Rm & 3) + kk) * 168 + ch * 32 + quad * 8;
                bf16x8 ah = *(const bf16x8*)(sAh + phys);
                bf16x8 al = *(const bf16x8*)(sAl + phys);
                #pragma unroll
                for (int q2 = 0; q2 < 2; ++q2) {
                    acc[mt][q2] = MFMA(ah, bh[q2], acc[mt][q2]);
                    acc[mt][q2] = MFMA(ah, bl_[q2], acc[mt][q2]);
                    acc[mt][q2] = MFMA(al, bh[q2], acc[mt][q2]);
                }
            }
        }
    }
    #pragma unroll
    for (int q2 = 0; q2 < 2; ++q2) {
        int n = (w * 2 + q2) * 16 + m;
        float bv = b1[n];
        #pragma unroll
        for (int mt = 0; mt < 4; ++mt)
            #pragma unroll
            for (int r = 0; r < 4; ++r) {
                int R = mt * 16 + quad * 4 + r;
                act[(size_t)(b0 + (R >> 2)) * 640 + (R & 3) * 128 + n] = fmaxf(acc[mt][q2][r] + bv, 0.f);
            }
    }
}

// ---------------- k_gemm: generic relu(A*B+bias), frag-linear A LDS, barrier-free ----------------
// block 128 (2 waves), 32 batches (MT=2), dual config via blockIdx.y
__global__ __launch_bounds__(128) void k_gemm(float* __restrict__ act,
                                              int awoffA, int nchA, const u16* __restrict__ BfA, int bszA, int ooffA,
                                              int awoffB, int nchB, const u16* __restrict__ BfB, int bszB, int ooffB,
                                              int ntiles, const float* __restrict__ bias) {
    __shared__ __align__(16) u16 sAh[32 * 384];
    __shared__ __align__(16) u16 sAl[32 * 384];
    const int cfg = blockIdx.y;
    const int awoff = cfg ? awoffB : awoffA;
    const int nch = cfg ? nchB : nchA;
    const u16* Bf = cfg ? BfB : BfA;
    const int bsz = cfg ? bszB : bszA;
    const int ooff = cfg ? ooffB : ooffA;
    const int tid = threadIdx.x;
    const int b0 = blockIdx.x << 5;
    const int kd4 = nch << 3;                       // K/4
    for (int i = tid; i < 32 * kd4; i += 128) {
        int row = i / kd4, k4 = (i - row * kd4) * 4;
        float4 v = *(const float4*)(act + (size_t)(b0 + row) * 640 + awoff + k4);
        int mt = row >> 4, mm = row & 15, ch = k4 >> 5, q = (k4 >> 3) & 3, e = k4 & 7;
        int phys = ((mt * nch + ch) * 64 + q * 16 + mm) * 8 + e;
        split_store4(v, sAh + phys, sAl + phys);
    }
    __syncthreads();
    const int lane = tid & 63, w = tid >> 6;
    const int m = lane & 15, quad = lane >> 4;
    const int NT = ntiles >> 1;
    f32x4 acc[2][4];
    #pragma unroll
    for (int mt = 0; mt < 2; ++mt)
        #pragma unroll
        for (int t = 0; t < 4; ++t) acc[mt][t] = (f32x4){0.f, 0.f, 0.f, 0.f};
    for (int ch = 0; ch < nch; ++ch) {
        bf16x8 ah[2], al[2];
        #pragma unroll
        for (int mt = 0; mt < 2; ++mt) {
            int phys = ((mt * nch + ch) * 64 + lane) * 8;
            ah[mt] = *(const bf16x8*)(sAh + phys);
            al[mt] = *(const bf16x8*)(sAl + phys);
        }
        #pragma unroll
        for (int tt = 0; tt < 4; ++tt) {
            if (tt < NT) {
                int t = w * NT + tt;
                bf16x8 bh = bfrag(Bf, t, ch, nch, lane);
                bf16x8 bl_ = bfrag(Bf + bsz, t, ch, nch, lane);
                #pragma unroll
                for (int mt = 0; mt < 2; ++mt) {
                    acc[mt][tt] = MFMA(ah[mt], bh, acc[mt][tt]);
                    acc[mt][tt] = MFMA(ah[mt], bl_, acc[mt][tt]);
                    acc[mt][tt] = MFMA(al[mt], bh, acc[mt][tt]);
                }
            }
        }
    }
    #pragma unroll
    for (int tt = 0; tt < 4; ++tt) {
        if (tt < NT) {
            int n = (w * NT + tt) * 16 + m;
            float bv = bias[n];
            #pragma unroll
            for (int mt = 0; mt < 2; ++mt)
                #pragma unroll
                for (int r = 0; r < 4; ++r) {
                    int R = mt * 16 + quad * 4 + r;
                    act[(size_t)(b0 + R) * 640 + ooff + n] = fmaxf(acc[mt][tt][r] + bv, 0.f);
                }
        }
    }
}

// ---------------- k_lstm: split GEMM M=8192 K=256 N=512 + fused cell/head, barrier-free ----------------
// block 256 (4 waves, each: all 4 gates x 2 j-tiles), 16 batches (MT=1), grid 512
__global__ __launch_bounds__(256) void k_lstm(const float* __restrict__ act, const float* __restrict__ hin,
                                              const u16* __restrict__ BL,
                                              const float* __restrict__ cin,
                                              const float* __restrict__ bxi, const float* __restrict__ bxf,
                                              const float* __restrict__ bxg, const float* __restrict__ bxo,
                                              const float* __restrict__ bhi, const float* __restrict__ bhf,
                                              const float* __restrict__ bhg, const float* __restrict__ bho,
                                              const float* __restrict__ cw, const float* __restrict__ cb,
                                              float* __restrict__ out) {
    __shared__ __align__(16) u16 sAh[8 * 512];
    __shared__ __align__(16) u16 sAl[8 * 512];
    __shared__ float pr[4][16];
    const int tid = threadIdx.x;
    const int b0 = blockIdx.x << 4;
    for (int i = tid; i < 16 * 64; i += 256) {
        int row = i >> 6, k4 = (i & 63) * 4;
        float4 v = (k4 < 128) ? *(const float4*)(act + (size_t)(b0 + row) * 640 + 64 + k4)
                              : *(const float4*)(hin + (size_t)(b0 + row) * 128 + (k4 - 128));
        int ch = k4 >> 5, q = (k4 >> 3) & 3, e = k4 & 7;
        int phys = (ch * 64 + q * 16 + row) * 8 + e;
        split_store4(v, sAh + phys, sAl + phys);
    }
    __syncthreads();
    const int lane = tid & 63, w = tid >> 6;
    const int m = lane & 15, quad = lane >> 4;
    f32x4 acc[4][2];
    #pragma unroll
    for (int g = 0; g < 4; ++g) { acc[g][0] = (f32x4){0,0,0,0}; acc[g][1] = (f32x4){0,0,0,0}; }
    for (int ch = 0; ch < 8; ++ch) {
        int phys = (ch * 64 + lane) * 8;
        bf16x8 ah = *(const bf16x8*)(sAh + phys);
        bf16x8 al = *(const bf16x8*)(sAl + phys);
        #pragma unroll
        for (int g = 0; g < 4; ++g)
            #pragma unroll
            for (int q2 = 0; q2 < 2; ++q2) {
                int nt = g * 8 + w * 2 + q2;
                bf16x8 bh = bfrag(BL, nt, ch, 8, lane);
                bf16x8 bl_ = bfrag(BL + S_BL, nt, ch, 8, lane);
                acc[g][q2] = MFMA(ah, bh, acc[g][q2]);
                acc[g][q2] = MFMA(ah, bl_, acc[g][q2]);
                acc[g][q2] = MFMA(al, bh, acc[g][q2]);
            }
    }
    float partial[4] = {0.f, 0.f, 0.f, 0.f};
    #pragma unroll
    for (int q2 = 0; q2 < 2; ++q2) {
        const int j = (w * 2 + q2) * 16 + m;
        const float bi = bxi[j] + bhi[j];
        const float bff = bxf[j] + bhf[j];
        const float bgg = bxg[j] + bhg[j];
        const float boo = bxo[j] + bho[j];
        const float cwj = cw[j];
        #pragma unroll
        for (int r = 0; r < 4; ++r) {
            const int b = b0 + quad * 4 + r;
            const float ig = sigm(acc[0][q2][r] + bi);
            const float fg = sigm(acc[1][q2][r] + bff);
            const float gg = tanhf(acc[2][q2][r] + bgg);
            const float og = sigm(acc[3][q2][r] + boo);
            const float ci = cin[(size_t)b * 128 + j];
            const float co = fg * ci + ig * gg;
            const float ho = og * tanhf(co);
            out[(size_t)BATCH + (size_t)b * 128 + j] = ho;
            out[(size_t)BATCH + (size_t)BATCH * 128 + (size_t)b * 128 + j] = co;
            partial[r] += fmaxf(ho, 0.f) * cwj;
        }
    }
    #pragma unroll
    for (int off = 1; off < 16; off <<= 1)
        #pragma unroll
        for (int r = 0; r < 4; ++r) partial[r] += __shfl_xor(partial[r], off);
    if (m == 0) {
        #pragma unroll
        for (int r = 0; r < 4; ++r) pr[w][quad * 4 + r] = partial[r];
    }
    __syncthreads();
    if (tid < 16)
        out[b0 + tid] = sigm(pr[0][tid] + pr[1][tid] + pr[2][tid] + pr[3][tid] + cb[0]);
}

extern "C" void kernel_launch(void* const* d_in, const int* in_sizes, int n_in,
                              void* d_out, int out_size, void* d_ws, size_t ws_size,
                              hipStream_t stream) {
    const float* audio = (const float*)d_in[0];
    const float* hin   = (const float*)d_in[1];
    const float* cin   = (const float*)d_in[2];
    const float* fb    = (const float*)d_in[3];
    const float* w1    = (const float*)d_in[4];
    const float* b1    = (const float*)d_in[5];
    const float* w2    = (const float*)d_in[6];
    const float* b2    = (const float*)d_in[7];
    const float* w3    = (const float*)d_in[8];
    const float* b3    = (const float*)d_in[9];
    const float* w4    = (const float*)d_in[10];
    const float* b4    = (const float*)d_in[11];
    const float* wi    = (const float*)d_in[12];
    const float* wf    = (const float*)d_in[13];
    const float* wg    = (const float*)d_in[14];
    const float* wo    = (const float*)d_in[15];
    const float* ui    = (const float*)d_in[16];
    const float* uf    = (const float*)d_in[17];
    const float* ug    = (const float*)d_in[18];
    const float* uo    = (const float*)d_in[19];
    const float* bxi   = (const float*)d_in[20];
    const float* bxf   = (const float*)d_in[21];
    const float* bxg   = (const float*)d_in[22];
    const float* bxo   = (const float*)d_in[23];
    const float* bhi   = (const float*)d_in[24];
    const float* bhf   = (const float*)d_in[25];
    const float* bhg   = (const float*)d_in[26];
    const float* bho   = (const float*)d_in[27];
    const float* cw    = (const float*)d_in[28];
    const float* cb    = (const float*)d_in[29];
    float* out = (float*)d_out;

    u16* wsu = (u16*)d_ws;
    float* ACT = (float*)(wsu + WEND);           // [8192][640] fp32

    k_prep<<<640, 256, 0, stream>>>(fb, w1, w2, w3, w4, wi, wf, wg, wo, ui, uf, ug, uo, wsu);
    k_stft<<<BATCH / 16, 256, 0, stream>>>(audio, wsu + P_FBT, ACT);
    k_enc1<<<BATCH / 16, 256, 0, stream>>>(ACT, wsu + P_B1, b1);
    k_gemm<<<dim3(BATCH / 32, 2), 128, 0, stream>>>(ACT,
                                                    0,   8,  wsu + P_B2A, S_B2A, 512,
                                                    128, 12, wsu + P_B2B, S_B2B, 576,
                                                    4, b2);
    k_gemm<<<dim3(BATCH / 32, 1), 128, 0, stream>>>(ACT,
                                                    512, 4, wsu + P_B3, S_B3, 0,
                                                    512, 4, wsu + P_B3, S_B3, 0,
                                                    4, b3);
    k_gemm<<<dim3(BATCH / 32, 1), 128, 0, stream>>>(ACT,
                                                    0, 2, wsu + P_B4, S_B4, 64,
                                                    0, 2, wsu + P_B4, S_B4, 64,
                                                    8, b4);
    k_lstm<<<BATCH / 16, 256, 0, stream>>>(ACT, hin, wsu + P_BL, cin,
                                           bxi, bxf, bxg, bxo, bhi, bhf, bhg, bho,
                                           cw, cb, out);
}

// Round 6
// 205.859 us; speedup vs baseline: 4.7976x; 1.2367x over previous
//
#include <hip/hip_runtime.h>
#include <math.h>

#define BATCH 8192
typedef unsigned short u16;
typedef unsigned int u32;
typedef __attribute__((ext_vector_type(8))) short bf16x8;
typedef __attribute__((ext_vector_type(4))) float f32x4;
typedef __attribute__((ext_vector_type(4))) unsigned short u16x4;

__device__ __forceinline__ float sigm(float v) { return 1.0f / (1.0f + __expf(-v)); }
__device__ __forceinline__ u16 f2bf(float f) {
    union { float f; u32 u; } v; v.f = f;
    u32 r = v.u + 0x7FFFu + ((v.u >> 16) & 1u);   // RNE
    return (u16)(r >> 16);
}
__device__ __forceinline__ float bf2f(u16 h) {
    union { u32 u; float f; } v; v.u = ((u32)h) << 16; return v.f;
}
__device__ __forceinline__ void split_store4(float4 v, u16* hp, u16* lp) {
    u16 h0 = f2bf(v.x), h1 = f2bf(v.y), h2 = f2bf(v.z), h3 = f2bf(v.w);
    u16x4 hv = {h0, h1, h2, h3};
    u16x4 lv = {f2bf(v.x - bf2f(h0)), f2bf(v.y - bf2f(h1)),
                f2bf(v.z - bf2f(h2)), f2bf(v.w - bf2f(h3))};
    *(u16x4*)hp = hv; *(u16x4*)lp = lv;
}
// fragment-linear B: element [(nt*nch + ch)*64 + lane]*8 + e  ==  B[nt*16+(lane&15)][ch*32+(lane>>4)*8+e]
__device__ __forceinline__ bf16x8 bfrag(const u16* Bf, int nt, int ch, int nch, int lane) {
    return *(const bf16x8*)(Bf + (((size_t)nt * nch + ch) * 64 + lane) * 8);
}
#define MFMA(a, b, c) __builtin_amdgcn_mfma_f32_16x16x32_bf16(a, b, c, 0, 0, 0)

// ---------------- workspace layout (u16 elements); hi plane then lo plane ----------------
#define S_FBT 69632   // [17 nt][8 ch] frag-linear, n<272, k<256
#define S_B1  61440   // 3 taps x [8 nt][5 ch], n<128, k<160
#define S_B2A 16384   // [4 nt][8 ch]
#define S_B2B 24576   // [4 nt][12 ch]
#define S_B3  8192    // [4 nt][4 ch]
#define S_B4  8192    // [8 nt][2 ch]
#define S_BL  131072  // [32 nt][8 ch]  n = gate*128+j, k: 0..127 W / 128..255 U
#define P_FBT 0
#define P_B1  139264
#define P_B2A 262144
#define P_B2B 294912
#define P_B3  344064
#define P_B4  360448
#define P_BL  376832
#define WEND  638976
#define N_PREP 319488
// ACT fp32 [8192][640]: stft->mag(4x160); enc1->e1[0..511]; enc2->[512..639];
// enc3->[0..63]; enc4->x[64..191]; lstm reads x + hin.

// ---------------- k_prep: build fragment-linear split-bf16 B planes ----------------
__global__ __launch_bounds__(256) void k_prep(const float* __restrict__ fb,
                                              const float* __restrict__ w1, const float* __restrict__ w2,
                                              const float* __restrict__ w3, const float* __restrict__ w4,
                                              const float* __restrict__ wi, const float* __restrict__ wf,
                                              const float* __restrict__ wg, const float* __restrict__ wo,
                                              const float* __restrict__ ui, const float* __restrict__ uf,
                                              const float* __restrict__ ug, const float* __restrict__ uo,
                                              u16* __restrict__ wsu) {
    const float* Ws[8] = {wi, wf, wg, wo, ui, uf, ug, uo};
    for (int i = blockIdx.x * 256 + threadIdx.x; i < N_PREP; i += gridDim.x * 256) {
        int r = i;
        float v; int P, S, idx;
        if (r < S_FBT) {                                    // FBT nch=8
            int f = r >> 9, lane = (r & 511) >> 3, e = r & 7;
            int n = (f >> 3) * 16 + (lane & 15), k = (f & 7) * 32 + (lane >> 4) * 8 + e;
            int c = n >> 1, part = n & 1;
            v = (n < 258) ? fb[(size_t)(c + part * 129) * 256 + k] : 0.f;
            P = P_FBT; S = S_FBT; idx = r;
        } else if ((r -= S_FBT) < S_B1) {                   // B1: 3 taps, nch=5
            int kk = r / 20480, r2 = r - kk * 20480;
            int f = r2 >> 9, lane = (r2 & 511) >> 3, e = r2 & 7;
            int n = (f / 5) * 16 + (lane & 15), k = (f % 5) * 32 + (lane >> 4) * 8 + e;
            v = (k < 129) ? w1[(size_t)n * 387 + k * 3 + kk] : 0.f;
            P = P_B1; S = S_B1; idx = r;
        } else if ((r -= S_B1) < S_B2A) {                   // B2A nch=8
            int f = r >> 9, lane = (r & 511) >> 3, e = r & 7;
            int n = (f >> 3) * 16 + (lane & 15), k = (f & 7) * 32 + (lane >> 4) * 8 + e;
            v = w2[(size_t)n * 384 + (k & 127) * 3 + (k >> 7) + 1];
            P = P_B2A; S = S_B2A; idx = r;
        } else if ((r -= S_B2A) < S_B2B) {                  // B2B nch=12
            int f = r >> 9, lane = (r & 511) >> 3, e = r & 7;
            int n = (f / 12) * 16 + (lane & 15), k = (f % 12) * 32 + (lane >> 4) * 8 + e;
            v = w2[(size_t)n * 384 + (k & 127) * 3 + (k >> 7)];
            P = P_B2B; S = S_B2B; idx = r;
        } else if ((r -= S_B2B) < S_B3) {                   // B3 nch=4
            int f = r >> 9, lane = (r & 511) >> 3, e = r & 7;
            int n = (f >> 2) * 16 + (lane & 15), k = (f & 3) * 32 + (lane >> 4) * 8 + e;
            v = w3[(size_t)n * 192 + (k & 63) * 3 + (k >> 6) + 1];
            P = P_B3; S = S_B3; idx = r;
        } else if ((r -= S_B3) < S_B4) {                    // B4 nch=2
            int f = r >> 9, lane = (r & 511) >> 3, e = r & 7;
            int n = (f >> 1) * 16 + (lane & 15), k = (f & 1) * 32 + (lane >> 4) * 8 + e;
            v = w4[(size_t)n * 192 + k * 3 + 1];
            P = P_B4; S = S_B4; idx = r;
        } else {                                            // BL nch=8
            r -= S_B4;
            int f = r >> 9, lane = (r & 511) >> 3, e = r & 7;
            int n = (f >> 3) * 16 + (lane & 15), k = (f & 7) * 32 + (lane >> 4) * 8 + e;
            int g = n >> 7, j = n & 127;
            v = Ws[g + ((k >= 128) ? 4 : 0)][(size_t)j * 128 + (k & 127)];
            P = P_BL; S = S_BL; idx = r;
        }
        u16 h = f2bf(v);
        wsu[P + idx] = h;
        wsu[P + S + idx] = f2bf(v - bf2f(h));
    }
}

// ---------------- k_stft: split GEMM M=32768 K=256 N=272, barrier-free K-loop ----------------
// block 512 (8 waves = 2 rg x 4 nh), 16 batches (64 rows), grid 512
// A LDS layout: per batch 680 u16, phys = bl*680 + pos + (pos>>7)*8  (pos = t*128+k)
__global__ __launch_bounds__(512) void k_stft(const float* __restrict__ audio,
                                              const u16* __restrict__ fbT,
                                              float* __restrict__ act) {
    __shared__ __align__(16) u16 sAh[16 * 680];
    __shared__ __align__(16) u16 sAl[16 * 680];
    const int tid = threadIdx.x;
    const int b0 = blockIdx.x << 4;
    for (int i = tid; i < 16 * 4 * 24; i += 512) {          // zero mag cols 136..159
        int rr = i / 24, c = 136 + (i - rr * 24);
        act[(size_t)(b0 + (rr >> 2)) * 640 + (rr & 3) * 160 + c] = 0.f;
    }
    for (int i = tid; i < 16 * 160; i += 512) {
        int bb = i / 160, j4 = (i - bb * 160) * 4;
        const float* ap = audio + (size_t)(b0 + bb) * 576;
        float4 v;
        if (j4 < 576) v = *(const float4*)(ap + j4);
        else { v.x = ap[1150 - j4]; v.y = ap[1149 - j4]; v.z = ap[1148 - j4]; v.w = ap[1147 - j4]; }
        int phys = bb * 680 + j4 + (j4 >> 7) * 8;
        split_store4(v, sAh + phys, sAl + phys);
    }
    __syncthreads();
    const int lane = tid & 63, w = tid >> 6;
    const int m = lane & 15, quad = lane >> 4;
    const int rg = w & 1, nh = w >> 1;                      // rg: 2 row groups, nh: 4 n-groups
    const int tbase = (nh == 0) ? 0 : (4 * nh + 1);
    const int tcnt = (nh == 0) ? 5 : 4;
    f32x4 acc[2][5];
    #pragma unroll
    for (int mt = 0; mt < 2; ++mt)
        #pragma unroll
        for (int t = 0; t < 5; ++t) acc[mt][t] = (f32x4){0.f, 0.f, 0.f, 0.f};
    for (int ch = 0; ch < 8; ++ch) {
        bf16x8 ah[2], al[2];
        #pragma unroll
        for (int mt = 0; mt < 2; ++mt) {
            int Rm = rg * 32 + mt * 16 + m;
            int phys = (Rm >> 2) * 680 + (Rm & 3) * 136 + ch * 32 + quad * 8 + ((ch >= 4) ? 8 : 0);
            ah[mt] = *(const bf16x8*)(sAh + phys);
            al[mt] = *(const bf16x8*)(sAl + phys);
        }
        #pragma unroll
        for (int tt = 0; tt < 5; ++tt) {
            if (tt < tcnt) {
                int t = tbase + tt;
                bf16x8 bh = bfrag(fbT, t, ch, 8, lane);
                bf16x8 bl_ = bfrag(fbT + S_FBT, t, ch, 8, lane);
                #pragma unroll
                for (int mt = 0; mt < 2; ++mt) {
                    acc[mt][tt] = MFMA(ah[mt], bh, acc[mt][tt]);
                    acc[mt][tt] = MFMA(ah[mt], bl_, acc[mt][tt]);
                    acc[mt][tt] = MFMA(al[mt], bh, acc[mt][tt]);
                }
            }
        }
    }
    #pragma unroll
    for (int tt = 0; tt < 5; ++tt) {
        if (tt < tcnt) {
            int n = (tbase + tt) * 16 + m;
            #pragma unroll
            for (int mt = 0; mt < 2; ++mt)
                #pragma unroll
                for (int r = 0; r < 4; ++r) {
                    float vv = acc[mt][tt][r];
                    float s = vv * vv;
                    s += __shfl_xor(s, 1);
                    if (!(n & 1)) {
                        int R = rg * 32 + mt * 16 + quad * 4 + r;
                        act[(size_t)(b0 + (R >> 2)) * 640 + (R & 3) * 160 + (n >> 1)] = sqrtf(s);
                    }
                }
        }
    }
}

// ---------------- k_enc1: 3-tap split GEMM, barrier-free K-loop ----------------
// block 512 (8 waves = 2 rg x 4 nh x 2 tiles), 16 batches (64 rows), grid 512
// A LDS: rows (bl*6 + tp), stride 168
__global__ __launch_bounds__(512) void k_enc1(float* __restrict__ act,
                                              const u16* __restrict__ B1w,
                                              const float* __restrict__ b1) {
    __shared__ __align__(16) u16 sAh[16 * 6 * 168];
    __shared__ __align__(16) u16 sAl[16 * 6 * 168];
    const int tid = threadIdx.x;
    const int b0 = blockIdx.x << 4;
    for (int i = tid; i < 16 * 6 * 40; i += 512) {
        int bb = i / 240, rem = i - bb * 240;
        int tp = rem / 40, c4 = (rem - tp * 40) * 4;
        float4 v = {0.f, 0.f, 0.f, 0.f};
        if (tp >= 1 && tp <= 4)
            v = *(const float4*)(act + (size_t)(b0 + bb) * 640 + (tp - 1) * 160 + c4);
        int phys = (bb * 6 + tp) * 168 + c4;
        split_store4(v, sAh + phys, sAl + phys);
    }
    __syncthreads();
    const int lane = tid & 63, w = tid >> 6;
    const int m = lane & 15, quad = lane >> 4;
    const int rg = w & 1, nh = w >> 1;                      // nh: 4 groups x 2 tiles
    f32x4 acc[2][2];
    #pragma unroll
    for (int mt = 0; mt < 2; ++mt) { acc[mt][0] = (f32x4){0,0,0,0}; acc[mt][1] = (f32x4){0,0,0,0}; }
    for (int kk = 0; kk < 3; ++kk) {
        const u16* Bh = B1w + kk * 20480;
        const u16* Bl = B1w + S_B1 + kk * 20480;
        for (int ch = 0; ch < 5; ++ch) {
            bf16x8 bh[2], bl_[2];
            #pragma unroll
            for (int q2 = 0; q2 < 2; ++q2) {
                bh[q2] = bfrag(Bh, nh * 2 + q2, ch, 5, lane);
                bl_[q2] = bfrag(Bl, nh * 2 + q2, ch, 5, lane);
            }
            #pragma unroll
            for (int mt = 0; mt < 2; ++mt) {
                int Rm = rg * 32 + mt * 16 + m;
                int phys = ((Rm >> 2) * 6 + (Rm & 3) + kk) * 168 + ch * 32 + quad * 8;
                bf16x8 ah = *(const bf16x8*)(sAh + phys);
                bf16x8 al = *(const bf16x8*)(sAl + phys);
                #pragma unroll
                for (int q2 = 0; q2 < 2; ++q2) {
                    acc[mt][q2] = MFMA(ah, bh[q2], acc[mt][q2]);
                    acc[mt][q2] = MFMA(ah, bl_[q2], acc[mt][q2]);
                    acc[mt][q2] = MFMA(al, bh[q2], acc[mt][q2]);
                }
            }
        }
    }
    #pragma unroll
    for (int q2 = 0; q2 < 2; ++q2) {
        int n = (nh * 2 + q2) * 16 + m;
        float bv = b1[n];
        #pragma unroll
        for (int mt = 0; mt < 2; ++mt)
            #pragma unroll
            for (int r = 0; r < 4; ++r) {
                int R = rg * 32 + mt * 16 + quad * 4 + r;
                act[(size_t)(b0 + (R >> 2)) * 640 + (R & 3) * 128 + n] = fmaxf(acc[mt][q2][r] + bv, 0.f);
            }
    }
}

// ---------------- k_gemm: generic relu(A*B+bias), frag-linear A LDS, barrier-free ----------------
// block 128 (2 waves), 16 batches (MT=1), dual config via blockIdx.y
__global__ __launch_bounds__(128) void k_gemm(float* __restrict__ act,
                                              int awoffA, int nchA, const u16* __restrict__ BfA, int bszA, int ooffA,
                                              int awoffB, int nchB, const u16* __restrict__ BfB, int bszB, int ooffB,
                                              int ntiles, const float* __restrict__ bias) {
    __shared__ __align__(16) u16 sAh[12 * 512];
    __shared__ __align__(16) u16 sAl[12 * 512];
    const int cfg = blockIdx.y;
    const int awoff = cfg ? awoffB : awoffA;
    const int nch = cfg ? nchB : nchA;
    const u16* Bf = cfg ? BfB : BfA;
    const int bsz = cfg ? bszB : bszA;
    const int ooff = cfg ? ooffB : ooffA;
    const int tid = threadIdx.x;
    const int b0 = blockIdx.x << 4;
    const int kd4 = nch << 3;                       // K/4
    for (int i = tid; i < 16 * kd4; i += 128) {
        int row = i / kd4, k4 = (i - row * kd4) * 4;
        float4 v = *(const float4*)(act + (size_t)(b0 + row) * 640 + awoff + k4);
        int ch = k4 >> 5, q = (k4 >> 3) & 3, e = k4 & 7;
        int phys = (ch * 64 + q * 16 + row) * 8 + e;
        split_store4(v, sAh + phys, sAl + phys);
    }
    __syncthreads();
    const int lane = tid & 63, w = tid >> 6;
    const int m = lane & 15, quad = lane >> 4;
    const int NT = ntiles >> 1;
    f32x4 acc[4];
    #pragma unroll
    for (int t = 0; t < 4; ++t) acc[t] = (f32x4){0.f, 0.f, 0.f, 0.f};
    for (int ch = 0; ch < nch; ++ch) {
        int phys = (ch * 64 + lane) * 8;
        bf16x8 ah = *(const bf16x8*)(sAh + phys);
        bf16x8 al = *(const bf16x8*)(sAl + phys);
        #pragma unroll
        for (int tt = 0; tt < 4; ++tt) {
            if (tt < NT) {
                int t = w * NT + tt;
                bf16x8 bh = bfrag(Bf, t, ch, nch, lane);
                bf16x8 bl_ = bfrag(Bf + bsz, t, ch, nch, lane);
                acc[tt] = MFMA(ah, bh, acc[tt]);
                acc[tt] = MFMA(ah, bl_, acc[tt]);
                acc[tt] = MFMA(al, bh, acc[tt]);
            }
        }
    }
    #pragma unroll
    for (int tt = 0; tt < 4; ++tt) {
        if (tt < NT) {
            int n = (w * NT + tt) * 16 + m;
            float bv = bias[n];
            #pragma unroll
            for (int r = 0; r < 4; ++r) {
                int R = quad * 4 + r;
                act[(size_t)(b0 + R) * 640 + ooff + n] = fmaxf(acc[tt][r] + bv, 0.f);
            }
        }
    }
}

// ---------------- k_lstm: split GEMM M=8192 K=256 N=512 + fused cell/head ----------------
// block 512 (8 waves, wave w owns j-tile w x all 4 gates), 16 batches (MT=1), grid 512
__global__ __launch_bounds__(512) void k_lstm(const float* __restrict__ act, const float* __restrict__ hin,
                                              const u16* __restrict__ BL,
                                              const float* __restrict__ cin,
                                              const float* __restrict__ bxi, const float* __restrict__ bxf,
                                              const float* __restrict__ bxg, const float* __restrict__ bxo,
                                              const float* __restrict__ bhi, const float* __restrict__ bhf,
                                              const float* __restrict__ bhg, const float* __restrict__ bho,
                                              const float* __restrict__ cw, const float* __restrict__ cb,
                                              float* __restrict__ out) {
    __shared__ __align__(16) u16 sAh[8 * 512];
    __shared__ __align__(16) u16 sAl[8 * 512];
    __shared__ float pr[8][16];
    const int tid = threadIdx.x;
    const int b0 = blockIdx.x << 4;
    for (int i = tid; i < 16 * 64; i += 512) {
        int row = i >> 6, k4 = (i & 63) * 4;
        float4 v = (k4 < 128) ? *(const float4*)(act + (size_t)(b0 + row) * 640 + 64 + k4)
                              : *(const float4*)(hin + (size_t)(b0 + row) * 128 + (k4 - 128));
        int ch = k4 >> 5, q = (k4 >> 3) & 3, e = k4 & 7;
        int phys = (ch * 64 + q * 16 + row) * 8 + e;
        split_store4(v, sAh + phys, sAl + phys);
    }
    __syncthreads();
    const int lane = tid & 63, w = tid >> 6;        // w = j-tile
    const int m = lane & 15, quad = lane >> 4;
    f32x4 acc[4];
    #pragma unroll
    for (int g = 0; g < 4; ++g) acc[g] = (f32x4){0.f, 0.f, 0.f, 0.f};
    for (int ch = 0; ch < 8; ++ch) {
        int phys = (ch * 64 + lane) * 8;
        bf16x8 ah = *(const bf16x8*)(sAh + phys);
        bf16x8 al = *(const bf16x8*)(sAl + phys);
        #pragma unroll
        for (int g = 0; g < 4; ++g) {
            int nt = g * 8 + w;
            bf16x8 bh = bfrag(BL, nt, ch, 8, lane);
            bf16x8 bl_ = bfrag(BL + S_BL, nt, ch, 8, lane);
            acc[g] = MFMA(ah, bh, acc[g]);
            acc[g] = MFMA(ah, bl_, acc[g]);
            acc[g] = MFMA(al, bh, acc[g]);
        }
    }
    float partial[4];
    const int j = w * 16 + m;
    const float bi = bxi[j] + bhi[j];
    const float bff = bxf[j] + bhf[j];
    const float bgg = bxg[j] + bhg[j];
    const float boo = bxo[j] + bho[j];
    const float cwj = cw[j];
    #pragma unroll
    for (int r = 0; r < 4; ++r) {
        const int b = b0 + quad * 4 + r;
        const float ig = sigm(acc[0][r] + bi);
        const float fg = sigm(acc[1][r] + bff);
        const float gg = tanhf(acc[2][r] + bgg);
        const float og = sigm(acc[3][r] + boo);
        const float ci = cin[(size_t)b * 128 + j];
        const float co = fg * ci + ig * gg;
        const float ho = og * tanhf(co);
        out[(size_t)BATCH + (size_t)b * 128 + j] = ho;
        out[(size_t)BATCH + (size_t)BATCH * 128 + (size_t)b * 128 + j] = co;
        partial[r] = fmaxf(ho, 0.f) * cwj;
    }
    #pragma unroll
    for (int off = 1; off < 16; off <<= 1)
        #pragma unroll
        for (int r = 0; r < 4; ++r) partial[r] += __shfl_xor(partial[r], off);
    if (m == 0) {
        #pragma unroll
        for (int r = 0; r < 4; ++r) pr[w][quad * 4 + r] = partial[r];
    }
    __syncthreads();
    if (tid < 16) {
        float s = cb[0];
        #pragma unroll
        for (int g = 0; g < 8; ++g) s += pr[g][tid];
        out[b0 + tid] = sigm(s);
    }
}

extern "C" void kernel_launch(void* const* d_in, const int* in_sizes, int n_in,
                              void* d_out, int out_size, void* d_ws, size_t ws_size,
                              hipStream_t stream) {
    const float* audio = (const float*)d_in[0];
    const float* hin   = (const float*)d_in[1];
    const float* cin   = (const float*)d_in[2];
    const float* fb    = (const float*)d_in[3];
    const float* w1    = (const float*)d_in[4];
    const float* b1    = (const float*)d_in[5];
    const float* w2    = (const float*)d_in[6];
    const float* b2    = (const float*)d_in[7];
    const float* w3    = (const float*)d_in[8];
    const float* b3    = (const float*)d_in[9];
    const float* w4    = (const float*)d_in[10];
    const float* b4    = (const float*)d_in[11];
    const float* wi    = (const float*)d_in[12];
    const float* wf    = (const float*)d_in[13];
    const float* wg    = (const float*)d_in[14];
    const float* wo    = (const float*)d_in[15];
    const float* ui    = (const float*)d_in[16];
    const float* uf    = (const float*)d_in[17];
    const float* ug    = (const float*)d_in[18];
    const float* uo    = (const float*)d_in[19];
    const float* bxi   = (const float*)d_in[20];
    const float* bxf   = (const float*)d_in[21];
    const float* bxg   = (const float*)d_in[22];
    const float* bxo   = (const float*)d_in[23];
    const float* bhi   = (const float*)d_in[24];
    const float* bhf   = (const float*)d_in[25];
    const float* bhg   = (const float*)d_in[26];
    const float* bho   = (const float*)d_in[27];
    const float* cw    = (const float*)d_in[28];
    const float* cb    = (const float*)d_in[29];
    float* out = (float*)d_out;

    u16* wsu = (u16*)d_ws;
    float* ACT = (float*)(wsu + WEND);           // [8192][640] fp32

    k_prep<<<640, 256, 0, stream>>>(fb, w1, w2, w3, w4, wi, wf, wg, wo, ui, uf, ug, uo, wsu);
    k_stft<<<BATCH / 16, 512, 0, stream>>>(audio, wsu + P_FBT, ACT);
    k_enc1<<<BATCH / 16, 512, 0, stream>>>(ACT, wsu + P_B1, b1);
    k_gemm<<<dim3(BATCH / 16, 2), 128, 0, stream>>>(ACT,
                                                    0,   8,  wsu + P_B2A, S_B2A, 512,
                                                    128, 12, wsu + P_B2B, S_B2B, 576,
                                                    4, b2);
    k_gemm<<<dim3(BATCH / 16, 1), 128, 0, stream>>>(ACT,
                                                    512, 4, wsu + P_B3, S_B3, 0,
                                                    512, 4, wsu + P_B3, S_B3, 0,
                                                    4, b3);
    k_gemm<<<dim3(BATCH / 16, 1), 128, 0, stream>>>(ACT,
                                                    0, 2, wsu + P_B4, S_B4, 64,
                                                    0, 2, wsu + P_B4, S_B4, 64,
                                                    8, b4);
    k_lstm<<<BATCH / 16, 512, 0, stream>>>(ACT, hin, wsu + P_BL, cin,
                                           bxi, bxf, bxg, bxo, bhi, bhf, bhg, bho,
                                           cw, cb, out);
}

// Round 7
// 188.043 us; speedup vs baseline: 5.2521x; 1.0947x over previous
//
#include <hip/hip_runtime.h>
#include <math.h>

#define BATCH 8192
typedef unsigned short u16;
typedef unsigned int u32;
typedef __attribute__((ext_vector_type(8))) short bf16x8;
typedef __attribute__((ext_vector_type(4))) float f32x4;
typedef __attribute__((ext_vector_type(4))) unsigned short u16x4;

__device__ __forceinline__ float sigm(float v) { return 1.0f / (1.0f + __expf(-v)); }
__device__ __forceinline__ u16 f2bf(float f) {
    union { float f; u32 u; } v; v.f = f;
    u32 r = v.u + 0x7FFFu + ((v.u >> 16) & 1u);   // RNE
    return (u16)(r >> 16);
}
__device__ __forceinline__ float bf2f(u16 h) {
    union { u32 u; float f; } v; v.u = ((u32)h) << 16; return v.f;
}
__device__ __forceinline__ void split_store4(float4 v, u16* hp, u16* lp) {
    u16 h0 = f2bf(v.x), h1 = f2bf(v.y), h2 = f2bf(v.z), h3 = f2bf(v.w);
    u16x4 hv = {h0, h1, h2, h3};
    u16x4 lv = {f2bf(v.x - bf2f(h0)), f2bf(v.y - bf2f(h1)),
                f2bf(v.z - bf2f(h2)), f2bf(v.w - bf2f(h3))};
    *(u16x4*)hp = hv; *(u16x4*)lp = lv;
}
// fragment-linear B: element [(nt*nch + ch)*64 + lane]*8 + e  ==  B[nt*16+(lane&15)][ch*32+(lane>>4)*8+e]
__device__ __forceinline__ bf16x8 bfrag(const u16* Bf, int nt, int ch, int nch, int lane) {
    return *(const bf16x8*)(Bf + (((size_t)nt * nch + ch) * 64 + lane) * 8);
}
#define MFMA(a, b, c) __builtin_amdgcn_mfma_f32_16x16x32_bf16(a, b, c, 0, 0, 0)

// ---------------- workspace layout (u16 elements); hi plane then lo plane ----------------
#define S_FBT 69632   // [17 nt][8 ch] frag-linear, n<272, k<256
#define S_B1  61440   // 3 taps x [8 nt][5 ch], n<128, k<160
#define S_B2A 16384   // [4 nt][8 ch]
#define S_B2B 24576   // [4 nt][12 ch]
#define S_B3  8192    // [4 nt][4 ch]
#define S_B4  8192    // [8 nt][2 ch]
#define S_BL  131072  // [32 nt][8 ch]  n = gate*128+j, k: 0..127 W / 128..255 U
#define P_FBT 0
#define P_B1  139264
#define P_B2A 262144
#define P_B2B 294912
#define P_B3  344064
#define P_B4  360448
#define P_BL  376832
#define WEND  638976
#define N_PREP 319488
// ACT fp32 [8192][512]: e1 only (the single inter-kernel activation buffer).

// ---------------- k_prep: build fragment-linear split-bf16 B planes ----------------
__global__ __launch_bounds__(256) void k_prep(const float* __restrict__ fb,
                                              const float* __restrict__ w1, const float* __restrict__ w2,
                                              const float* __restrict__ w3, const float* __restrict__ w4,
                                              const float* __restrict__ wi, const float* __restrict__ wf,
                                              const float* __restrict__ wg, const float* __restrict__ wo,
                                              const float* __restrict__ ui, const float* __restrict__ uf,
                                              const float* __restrict__ ug, const float* __restrict__ uo,
                                              u16* __restrict__ wsu) {
    const float* Ws[8] = {wi, wf, wg, wo, ui, uf, ug, uo};
    for (int i = blockIdx.x * 256 + threadIdx.x; i < N_PREP; i += gridDim.x * 256) {
        int r = i;
        float v; int P, S, idx;
        if (r < S_FBT) {                                    // FBT nch=8
            int f = r >> 9, lane = (r & 511) >> 3, e = r & 7;
            int n = (f >> 3) * 16 + (lane & 15), k = (f & 7) * 32 + (lane >> 4) * 8 + e;
            int c = n >> 1, part = n & 1;
            v = (n < 258) ? fb[(size_t)(c + part * 129) * 256 + k] : 0.f;
            P = P_FBT; S = S_FBT; idx = r;
        } else if ((r -= S_FBT) < S_B1) {                   // B1: 3 taps, nch=5
            int kk = r / 20480, r2 = r - kk * 20480;
            int f = r2 >> 9, lane = (r2 & 511) >> 3, e = r2 & 7;
            int n = (f / 5) * 16 + (lane & 15), k = (f % 5) * 32 + (lane >> 4) * 8 + e;
            v = (k < 129) ? w1[(size_t)n * 387 + k * 3 + kk] : 0.f;
            P = P_B1; S = S_B1; idx = r;
        } else if ((r -= S_B1) < S_B2A) {                   // B2A nch=8
            int f = r >> 9, lane = (r & 511) >> 3, e = r & 7;
            int n = (f >> 3) * 16 + (lane & 15), k = (f & 7) * 32 + (lane >> 4) * 8 + e;
            v = w2[(size_t)n * 384 + (k & 127) * 3 + (k >> 7) + 1];
            P = P_B2A; S = S_B2A; idx = r;
        } else if ((r -= S_B2A) < S_B2B) {                  // B2B nch=12
            int f = r >> 9, lane = (r & 511) >> 3, e = r & 7;
            int n = (f / 12) * 16 + (lane & 15), k = (f % 12) * 32 + (lane >> 4) * 8 + e;
            v = w2[(size_t)n * 384 + (k & 127) * 3 + (k >> 7)];
            P = P_B2B; S = S_B2B; idx = r;
        } else if ((r -= S_B2B) < S_B3) {                   // B3 nch=4
            int f = r >> 9, lane = (r & 511) >> 3, e = r & 7;
            int n = (f >> 2) * 16 + (lane & 15), k = (f & 3) * 32 + (lane >> 4) * 8 + e;
            v = w3[(size_t)n * 192 + (k & 63) * 3 + (k >> 6) + 1];
            P = P_B3; S = S_B3; idx = r;
        } else if ((r -= S_B3) < S_B4) {                    // B4 nch=2
            int f = r >> 9, lane = (r & 511) >> 3, e = r & 7;
            int n = (f >> 1) * 16 + (lane & 15), k = (f & 1) * 32 + (lane >> 4) * 8 + e;
            v = w4[(size_t)n * 192 + k * 3 + 1];
            P = P_B4; S = S_B4; idx = r;
        } else {                                            // BL nch=8
            r -= S_B4;
            int f = r >> 9, lane = (r & 511) >> 3, e = r & 7;
            int n = (f >> 3) * 16 + (lane & 15), k = (f & 7) * 32 + (lane >> 4) * 8 + e;
            int g = n >> 7, j = n & 127;
            v = Ws[g + ((k >= 128) ? 4 : 0)][(size_t)j * 128 + (k & 127)];
            P = P_BL; S = S_BL; idx = r;
        }
        u16 h = f2bf(v);
        wsu[P + idx] = h;
        wsu[P + S + idx] = f2bf(v - bf2f(h));
    }
}

// ---------------- k_fused1: STFT GEMM -> mag (LDS) -> enc1 GEMM -> e1 (ACT) ----------------
// block 512 (8 waves), 8 batches (32 rows), grid 1024.
// audio LDS: per batch 680 u16, phys = bb*680 + pos + (pos>>7)*8  (pos = t*128+k)
// mag LDS (enc1 A): rows bb*6 + tp (tp=t+1, rows 0,5 zero), stride 168, cols 0..135 mag, 136.. zero
__global__ __launch_bounds__(512) void k_fused1(const float* __restrict__ audio,
                                                const u16* __restrict__ wsu,
                                                const float* __restrict__ b1,
                                                float* __restrict__ act) {
    __shared__ __align__(16) u16 aAh[8 * 680];
    __shared__ __align__(16) u16 aAl[8 * 680];
    __shared__ __align__(16) u16 mAh[8 * 6 * 168];
    __shared__ __align__(16) u16 mAl[8 * 6 * 168];
    const int tid = threadIdx.x;
    const int b0 = blockIdx.x << 3;
    // zero mag planes (8064 u16 each = 4032 u32)
    for (int i = tid; i < 4032; i += 512) {
        ((u32*)mAh)[i] = 0u;
        ((u32*)mAl)[i] = 0u;
    }
    // stage audio (split bf16, reflect pad)
    for (int i = tid; i < 8 * 160; i += 512) {
        int bb = i / 160, j4 = (i - bb * 160) * 4;
        const float* ap = audio + (size_t)(b0 + bb) * 576;
        float4 v;
        if (j4 < 576) v = *(const float4*)(ap + j4);
        else { v.x = ap[1150 - j4]; v.y = ap[1149 - j4]; v.z = ap[1148 - j4]; v.w = ap[1147 - j4]; }
        int phys = bb * 680 + j4 + (j4 >> 7) * 8;
        split_store4(v, aAh + phys, aAl + phys);
    }
    __syncthreads();
    const int lane = tid & 63, w = tid >> 6;
    const int m = lane & 15, quad = lane >> 4;
    // ---- GEMM1 (STFT): wave w owns nt = 2w..2w+1 (w==7 also nt=16), mt=2 ----
    const u16* fbT = wsu + P_FBT;
    const int tcnt = (w == 7) ? 3 : 2;
    f32x4 acc[2][3];
    #pragma unroll
    for (int mt = 0; mt < 2; ++mt)
        #pragma unroll
        for (int t = 0; t < 3; ++t) acc[mt][t] = (f32x4){0.f, 0.f, 0.f, 0.f};
    for (int ch = 0; ch < 8; ++ch) {
        bf16x8 ah[2], al[2];
        #pragma unroll
        for (int mt = 0; mt < 2; ++mt) {
            int Rm = mt * 16 + m;
            int phys = (Rm >> 2) * 680 + (Rm & 3) * 136 + ch * 32 + quad * 8 + ((ch >= 4) ? 8 : 0);
            ah[mt] = *(const bf16x8*)(aAh + phys);
            al[mt] = *(const bf16x8*)(aAl + phys);
        }
        #pragma unroll
        for (int tt = 0; tt < 3; ++tt) {
            if (tt < tcnt) {
                int t = w * 2 + tt;
                bf16x8 bh = bfrag(fbT, t, ch, 8, lane);
                bf16x8 bl_ = bfrag(fbT + S_FBT, t, ch, 8, lane);
                #pragma unroll
                for (int mt = 0; mt < 2; ++mt) {
                    acc[mt][tt] = MFMA(ah[mt], bh, acc[mt][tt]);
                    acc[mt][tt] = MFMA(ah[mt], bl_, acc[mt][tt]);
                    acc[mt][tt] = MFMA(al[mt], bh, acc[mt][tt]);
                }
            }
        }
    }
    // magnitude epilogue -> mag LDS (split)
    #pragma unroll
    for (int tt = 0; tt < 3; ++tt) {
        if (tt < tcnt) {
            int n = (w * 2 + tt) * 16 + m;
            #pragma unroll
            for (int mt = 0; mt < 2; ++mt)
                #pragma unroll
                for (int r = 0; r < 4; ++r) {
                    float vv = acc[mt][tt][r];
                    float s = vv * vv;
                    s += __shfl_xor(s, 1);
                    if (!(n & 1)) {
                        int R = mt * 16 + quad * 4 + r;
                        int bb = R >> 2, t = R & 3, c = n >> 1;
                        float sv = sqrtf(s);
                        u16 h = f2bf(sv);
                        int phys = (bb * 6 + t + 1) * 168 + c;
                        mAh[phys] = h;
                        mAl[phys] = f2bf(sv - bf2f(h));
                    }
                }
        }
    }
    __syncthreads();
    // ---- GEMM2 (enc1): wave w owns nt = w (N=128), mt=2, K = 3 taps x 5 ch ----
    const u16* B1h = wsu + P_B1;
    const u16* B1l = wsu + P_B1 + S_B1;
    f32x4 acc2[2];
    acc2[0] = (f32x4){0.f, 0.f, 0.f, 0.f};
    acc2[1] = (f32x4){0.f, 0.f, 0.f, 0.f};
    for (int kk = 0; kk < 3; ++kk) {
        for (int ch = 0; ch < 5; ++ch) {
            bf16x8 bh = bfrag(B1h + kk * 20480, w, ch, 5, lane);
            bf16x8 bl_ = bfrag(B1l + kk * 20480, w, ch, 5, lane);
            #pragma unroll
            for (int mt = 0; mt < 2; ++mt) {
                int Rm = mt * 16 + m;
                int phys = ((Rm >> 2) * 6 + (Rm & 3) + kk) * 168 + ch * 32 + quad * 8;
                bf16x8 ah = *(const bf16x8*)(mAh + phys);
                bf16x8 al = *(const bf16x8*)(mAl + phys);
                acc2[mt] = MFMA(ah, bh, acc2[mt]);
                acc2[mt] = MFMA(ah, bl_, acc2[mt]);
                acc2[mt] = MFMA(al, bh, acc2[mt]);
            }
        }
    }
    {
        int n = w * 16 + m;
        float bv = b1[n];
        #pragma unroll
        for (int mt = 0; mt < 2; ++mt)
            #pragma unroll
            for (int r = 0; r < 4; ++r) {
                int R = mt * 16 + quad * 4 + r;
                act[(size_t)(b0 + (R >> 2)) * 512 + (R & 3) * 128 + n] = fmaxf(acc2[mt][r] + bv, 0.f);
            }
    }
}

// ---------------- k_fused2: enc2a/2b + enc3 + enc4 + LSTM + head, all in one block ----------------
// block 512 (8 waves), 16 batches (M=16), grid 512.
// LDS row-major A buffers, strides chosen == 4 mod 32 words (2-way conflicts only).
__global__ __launch_bounds__(512) void k_fused2(const float* __restrict__ act,
                                                const float* __restrict__ hin,
                                                const u16* __restrict__ wsu,
                                                const float* __restrict__ cin,
                                                const float* __restrict__ b2, const float* __restrict__ b3,
                                                const float* __restrict__ b4,
                                                const float* __restrict__ bxi, const float* __restrict__ bxf,
                                                const float* __restrict__ bxg, const float* __restrict__ bxo,
                                                const float* __restrict__ bhi, const float* __restrict__ bhf,
                                                const float* __restrict__ bhg, const float* __restrict__ bho,
                                                const float* __restrict__ cw, const float* __restrict__ cb,
                                                float* __restrict__ out) {
    __shared__ __align__(16) u16 eAh[16 * 520];
    __shared__ __align__(16) u16 eAl[16 * 520];
    __shared__ __align__(16) u16 s2h[16 * 136];
    __shared__ __align__(16) u16 s2l[16 * 136];
    __shared__ __align__(16) u16 s3h[16 * 72];
    __shared__ __align__(16) u16 s3l[16 * 72];
    __shared__ __align__(16) u16 xhh[16 * 264];
    __shared__ __align__(16) u16 xhl[16 * 264];
    __shared__ float pr[8][16];
    const int tid = threadIdx.x;
    const int b0 = blockIdx.x << 4;
    // stage e1 rows (split)
    for (int i = tid; i < 16 * 128; i += 512) {
        int row = i >> 7, c4 = (i & 127) * 4;
        float4 v = *(const float4*)(act + (size_t)(b0 + row) * 512 + c4);
        split_store4(v, eAh + row * 520 + c4, eAl + row * 520 + c4);
    }
    // stage h (split) into xh cols 128..255
    for (int i = tid; i < 16 * 32; i += 512) {
        int row = i >> 5, c4 = (i & 31) * 4;
        float4 v = *(const float4*)(hin + (size_t)(b0 + row) * 128 + c4);
        split_store4(v, xhh + row * 264 + 128 + c4, xhl + row * 264 + 128 + c4);
    }
    __syncthreads();
    const int lane = tid & 63, w = tid >> 6;
    const int m = lane & 15, quad = lane >> 4;
    // ---- enc2: waves 0-3 = enc2a (K=256), waves 4-7 = enc2b (K=384) ----
    {
        const int isB = w >> 2, nt = w & 3;
        const int awoff = isB ? 128 : 0;
        const int nch = isB ? 12 : 8;
        const u16* Bh = wsu + (isB ? P_B2B : P_B2A);
        const u16* Bl = Bh + (isB ? S_B2B : S_B2A);
        f32x4 acc = (f32x4){0.f, 0.f, 0.f, 0.f};
        for (int ch = 0; ch < nch; ++ch) {
            int phys = m * 520 + awoff + ch * 32 + quad * 8;
            bf16x8 ah = *(const bf16x8*)(eAh + phys);
            bf16x8 al = *(const bf16x8*)(eAl + phys);
            bf16x8 bh = bfrag(Bh, nt, ch, nch, lane);
            bf16x8 bl_ = bfrag(Bl, nt, ch, nch, lane);
            acc = MFMA(ah, bh, acc);
            acc = MFMA(ah, bl_, acc);
            acc = MFMA(al, bh, acc);
        }
        const int oc = nt * 16 + m;
        const float bv = b2[oc];
        const int col = isB * 64 + oc;
        #pragma unroll
        for (int r = 0; r < 4; ++r) {
            int row = quad * 4 + r;
            float vv = fmaxf(acc[r] + bv, 0.f);
            u16 h = f2bf(vv);
            s2h[row * 136 + col] = h;
            s2l[row * 136 + col] = f2bf(vv - bf2f(h));
        }
    }
    __syncthreads();
    // ---- enc3: waves 0-3, K=128 (4 ch), N=64 ----
    if (w < 4) {
        const u16* Bh = wsu + P_B3;
        const u16* Bl = Bh + S_B3;
        f32x4 acc = (f32x4){0.f, 0.f, 0.f, 0.f};
        for (int ch = 0; ch < 4; ++ch) {
            int phys = m * 136 + ch * 32 + quad * 8;
            bf16x8 ah = *(const bf16x8*)(s2h + phys);
            bf16x8 al = *(const bf16x8*)(s2l + phys);
            bf16x8 bh = bfrag(Bh, w, ch, 4, lane);
            bf16x8 bl_ = bfrag(Bl, w, ch, 4, lane);
            acc = MFMA(ah, bh, acc);
            acc = MFMA(ah, bl_, acc);
            acc = MFMA(al, bh, acc);
        }
        const int n = w * 16 + m;
        const float bv = b3[n];
        #pragma unroll
        for (int r = 0; r < 4; ++r) {
            int row = quad * 4 + r;
            float vv = fmaxf(acc[r] + bv, 0.f);
            u16 h = f2bf(vv);
            s3h[row * 72 + n] = h;
            s3l[row * 72 + n] = f2bf(vv - bf2f(h));
        }
    }
    __syncthreads();
    // ---- enc4: all 8 waves, K=64 (2 ch), N=128 -> x into xh cols 0..127 ----
    {
        const u16* Bh = wsu + P_B4;
        const u16* Bl = Bh + S_B4;
        f32x4 acc = (f32x4){0.f, 0.f, 0.f, 0.f};
        for (int ch = 0; ch < 2; ++ch) {
            int phys = m * 72 + ch * 32 + quad * 8;
            bf16x8 ah = *(const bf16x8*)(s3h + phys);
            bf16x8 al = *(const bf16x8*)(s3l + phys);
            bf16x8 bh = bfrag(Bh, w, ch, 2, lane);
            bf16x8 bl_ = bfrag(Bl, w, ch, 2, lane);
            acc = MFMA(ah, bh, acc);
            acc = MFMA(ah, bl_, acc);
            acc = MFMA(al, bh, acc);
        }
        const int n = w * 16 + m;
        const float bv = b4[n];
        #pragma unroll
        for (int r = 0; r < 4; ++r) {
            int row = quad * 4 + r;
            float vv = fmaxf(acc[r] + bv, 0.f);
            u16 h = f2bf(vv);
            xhh[row * 264 + n] = h;
            xhl[row * 264 + n] = f2bf(vv - bf2f(h));
        }
    }
    __syncthreads();
    // ---- LSTM: wave w owns j-tile w x all 4 gates; K=256 (8 ch) ----
    {
        const u16* BLh = wsu + P_BL;
        const u16* BLl = BLh + S_BL;
        f32x4 acc[4];
        #pragma unroll
        for (int g = 0; g < 4; ++g) acc[g] = (f32x4){0.f, 0.f, 0.f, 0.f};
        for (int ch = 0; ch < 8; ++ch) {
            int phys = m * 264 + ch * 32 + quad * 8;
            bf16x8 ah = *(const bf16x8*)(xhh + phys);
            bf16x8 al = *(const bf16x8*)(xhl + phys);
            #pragma unroll
            for (int g = 0; g < 4; ++g) {
                int nt = g * 8 + w;
                bf16x8 bh = bfrag(BLh, nt, ch, 8, lane);
                bf16x8 bl_ = bfrag(BLl, nt, ch, 8, lane);
                acc[g] = MFMA(ah, bh, acc[g]);
                acc[g] = MFMA(ah, bl_, acc[g]);
                acc[g] = MFMA(al, bh, acc[g]);
            }
        }
        float partial[4];
        const int j = w * 16 + m;
        const float bi = bxi[j] + bhi[j];
        const float bff = bxf[j] + bhf[j];
        const float bgg = bxg[j] + bhg[j];
        const float boo = bxo[j] + bho[j];
        const float cwj = cw[j];
        #pragma unroll
        for (int r = 0; r < 4; ++r) {
            const int b = b0 + quad * 4 + r;
            const float ig = sigm(acc[0][r] + bi);
            const float fg = sigm(acc[1][r] + bff);
            const float gg = tanhf(acc[2][r] + bgg);
            const float og = sigm(acc[3][r] + boo);
            const float ci = cin[(size_t)b * 128 + j];
            const float co = fg * ci + ig * gg;
            const float ho = og * tanhf(co);
            out[(size_t)BATCH + (size_t)b * 128 + j] = ho;
            out[(size_t)BATCH + (size_t)BATCH * 128 + (size_t)b * 128 + j] = co;
            partial[r] = fmaxf(ho, 0.f) * cwj;
        }
        #pragma unroll
        for (int off = 1; off < 16; off <<= 1)
            #pragma unroll
            for (int r = 0; r < 4; ++r) partial[r] += __shfl_xor(partial[r], off);
        if (m == 0) {
            #pragma unroll
            for (int r = 0; r < 4; ++r) pr[w][quad * 4 + r] = partial[r];
        }
    }
    __syncthreads();
    if (tid < 16) {
        float s = cb[0];
        #pragma unroll
        for (int g = 0; g < 8; ++g) s += pr[g][tid];
        out[b0 + tid] = sigm(s);
    }
}

extern "C" void kernel_launch(void* const* d_in, const int* in_sizes, int n_in,
                              void* d_out, int out_size, void* d_ws, size_t ws_size,
                              hipStream_t stream) {
    const float* audio = (const float*)d_in[0];
    const float* hin   = (const float*)d_in[1];
    const float* cin   = (const float*)d_in[2];
    const float* fb    = (const float*)d_in[3];
    const float* w1    = (const float*)d_in[4];
    const float* b1    = (const float*)d_in[5];
    const float* w2    = (const float*)d_in[6];
    const float* b2    = (const float*)d_in[7];
    const float* w3    = (const float*)d_in[8];
    const float* b3    = (const float*)d_in[9];
    const float* w4    = (const float*)d_in[10];
    const float* b4    = (const float*)d_in[11];
    const float* wi    = (const float*)d_in[12];
    const float* wf    = (const float*)d_in[13];
    const float* wg    = (const float*)d_in[14];
    const float* wo    = (const float*)d_in[15];
    const float* ui    = (const float*)d_in[16];
    const float* uf    = (const float*)d_in[17];
    const float* ug    = (const float*)d_in[18];
    const float* uo    = (const float*)d_in[19];
    const float* bxi   = (const float*)d_in[20];
    const float* bxf   = (const float*)d_in[21];
    const float* bxg   = (const float*)d_in[22];
    const float* bxo   = (const float*)d_in[23];
    const float* bhi   = (const float*)d_in[24];
    const float* bhf   = (const float*)d_in[25];
    const float* bhg   = (const float*)d_in[26];
    const float* bho   = (const float*)d_in[27];
    const float* cw    = (const float*)d_in[28];
    const float* cb    = (const float*)d_in[29];
    float* out = (float*)d_out;

    u16* wsu = (u16*)d_ws;
    float* ACT = (float*)(wsu + WEND);           // [8192][512] fp32 (e1)

    k_prep<<<640, 256, 0, stream>>>(fb, w1, w2, w3, w4, wi, wf, wg, wo, ui, uf, ug, uo, wsu);
    k_fused1<<<BATCH / 8, 512, 0, stream>>>(audio, wsu, b1, ACT);
    k_fused2<<<BATCH / 16, 512, 0, stream>>>(ACT, hin, wsu, cin, b2, b3, b4,
                                             bxi, bxf, bxg, bxo, bhi, bhf, bhg, bho,
                                             cw, cb, out);
}

// Round 8
// 181.436 us; speedup vs baseline: 5.4434x; 1.0364x over previous
//
#include <hip/hip_runtime.h>
#include <math.h>

#define BATCH 8192
typedef unsigned short u16;
typedef unsigned int u32;
typedef __attribute__((ext_vector_type(8))) short bf16x8;
typedef __attribute__((ext_vector_type(4))) float f32x4;
typedef __attribute__((ext_vector_type(4))) unsigned short u16x4;

__device__ __forceinline__ float sigm(float v) { return 1.0f / (1.0f + __expf(-v)); }
__device__ __forceinline__ u16 f2bf(float f) {
    union { float f; u32 u; } v; v.f = f;
    u32 r = v.u + 0x7FFFu + ((v.u >> 16) & 1u);   // RNE
    return (u16)(r >> 16);
}
__device__ __forceinline__ float bf2f(u16 h) {
    union { u32 u; float f; } v; v.u = ((u32)h) << 16; return v.f;
}
__device__ __forceinline__ void split_store4(float4 v, u16* hp, u16* lp) {
    u16 h0 = f2bf(v.x), h1 = f2bf(v.y), h2 = f2bf(v.z), h3 = f2bf(v.w);
    u16x4 hv = {h0, h1, h2, h3};
    u16x4 lv = {f2bf(v.x - bf2f(h0)), f2bf(v.y - bf2f(h1)),
                f2bf(v.z - bf2f(h2)), f2bf(v.w - bf2f(h3))};
    *(u16x4*)hp = hv; *(u16x4*)lp = lv;
}
// fragment-linear B: element [(nt*nch + ch)*64 + lane]*8 + e  ==  B[nt*16+(lane&15)][ch*32+(lane>>4)*8+e]
__device__ __forceinline__ bf16x8 bfrag(const u16* Bf, int nt, int ch, int nch, int lane) {
    return *(const bf16x8*)(Bf + (((size_t)nt * nch + ch) * 64 + lane) * 8);
}
#define MFMA(a, b, c) __builtin_amdgcn_mfma_f32_16x16x32_bf16(a, b, c, 0, 0, 0)

// ---------------- workspace layout (u16 elements); hi plane then lo plane ----------------
#define S_FBT 69632   // [17 nt][8 ch] frag-linear, n<272, k<256
#define S_B1  61440   // 3 taps x [8 nt][5 ch], n<128, k<160
#define S_B2A 16384   // [4 nt][8 ch]
#define S_B2B 24576   // [4 nt][12 ch]
#define S_B3  8192    // [4 nt][4 ch]
#define S_B4  8192    // [8 nt][2 ch]
#define S_BL  131072  // [32 nt][8 ch]  n = gate*128+j, k: 0..127 W / 128..255 U
#define P_FBT 0
#define P_B1  139264
#define P_B2A 262144
#define P_B2B 294912
#define P_B3  344064
#define P_B4  360448
#define P_BL  376832
#define WEND  638976
#define N_PREP 319488
// After weights: E1H [8192][512] u16, then E1L [8192][512] u16 (split-bf16 e1).

// ---------------- k_prep: build fragment-linear split-bf16 B planes ----------------
__global__ __launch_bounds__(256) void k_prep(const float* __restrict__ fb,
                                              const float* __restrict__ w1, const float* __restrict__ w2,
                                              const float* __restrict__ w3, const float* __restrict__ w4,
                                              const float* __restrict__ wi, const float* __restrict__ wf,
                                              const float* __restrict__ wg, const float* __restrict__ wo,
                                              const float* __restrict__ ui, const float* __restrict__ uf,
                                              const float* __restrict__ ug, const float* __restrict__ uo,
                                              u16* __restrict__ wsu) {
    const float* Ws[8] = {wi, wf, wg, wo, ui, uf, ug, uo};
    for (int i = blockIdx.x * 256 + threadIdx.x; i < N_PREP; i += gridDim.x * 256) {
        int r = i;
        float v; int P, S, idx;
        if (r < S_FBT) {                                    // FBT nch=8
            int f = r >> 9, lane = (r & 511) >> 3, e = r & 7;
            int n = (f >> 3) * 16 + (lane & 15), k = (f & 7) * 32 + (lane >> 4) * 8 + e;
            int c = n >> 1, part = n & 1;
            v = (n < 258) ? fb[(size_t)(c + part * 129) * 256 + k] : 0.f;
            P = P_FBT; S = S_FBT; idx = r;
        } else if ((r -= S_FBT) < S_B1) {                   // B1: 3 taps, nch=5
            int kk = r / 20480, r2 = r - kk * 20480;
            int f = r2 >> 9, lane = (r2 & 511) >> 3, e = r2 & 7;
            int n = (f / 5) * 16 + (lane & 15), k = (f % 5) * 32 + (lane >> 4) * 8 + e;
            v = (k < 129) ? w1[(size_t)n * 387 + k * 3 + kk] : 0.f;
            P = P_B1; S = S_B1; idx = r;
        } else if ((r -= S_B1) < S_B2A) {                   // B2A nch=8
            int f = r >> 9, lane = (r & 511) >> 3, e = r & 7;
            int n = (f >> 3) * 16 + (lane & 15), k = (f & 7) * 32 + (lane >> 4) * 8 + e;
            v = w2[(size_t)n * 384 + (k & 127) * 3 + (k >> 7) + 1];
            P = P_B2A; S = S_B2A; idx = r;
        } else if ((r -= S_B2A) < S_B2B) {                  // B2B nch=12
            int f = r >> 9, lane = (r & 511) >> 3, e = r & 7;
            int n = (f / 12) * 16 + (lane & 15), k = (f % 12) * 32 + (lane >> 4) * 8 + e;
            v = w2[(size_t)n * 384 + (k & 127) * 3 + (k >> 7)];
            P = P_B2B; S = S_B2B; idx = r;
        } else if ((r -= S_B2B) < S_B3) {                   // B3 nch=4
            int f = r >> 9, lane = (r & 511) >> 3, e = r & 7;
            int n = (f >> 2) * 16 + (lane & 15), k = (f & 3) * 32 + (lane >> 4) * 8 + e;
            v = w3[(size_t)n * 192 + (k & 63) * 3 + (k >> 6) + 1];
            P = P_B3; S = S_B3; idx = r;
        } else if ((r -= S_B3) < S_B4) {                    // B4 nch=2
            int f = r >> 9, lane = (r & 511) >> 3, e = r & 7;
            int n = (f >> 1) * 16 + (lane & 15), k = (f & 1) * 32 + (lane >> 4) * 8 + e;
            v = w4[(size_t)n * 192 + k * 3 + 1];
            P = P_B4; S = S_B4; idx = r;
        } else {                                            // BL nch=8
            r -= S_B4;
            int f = r >> 9, lane = (r & 511) >> 3, e = r & 7;
            int n = (f >> 3) * 16 + (lane & 15), k = (f & 7) * 32 + (lane >> 4) * 8 + e;
            int g = n >> 7, j = n & 127;
            v = Ws[g + ((k >= 128) ? 4 : 0)][(size_t)j * 128 + (k & 127)];
            P = P_BL; S = S_BL; idx = r;
        }
        u16 h = f2bf(v);
        wsu[P + idx] = h;
        wsu[P + S + idx] = f2bf(v - bf2f(h));
    }
}

// ---------------- k_fused1: STFT GEMM -> mag (LDS, aliased) -> enc1 GEMM -> e1 (split global) ----------------
// block 512 (8 waves), 16 batches (64 rows, mt=4), grid 512.
// audio LDS: per batch 720 u16 (stride 720: 360 w == 8 mod 32 -> free 2-way), layout 5 x 136 + pad
// mag LDS (aliased over audio after K-loop): rows bb*6 + tp, stride 168, cols 0..135 data
__global__ __launch_bounds__(512) void k_fused1(const float* __restrict__ audio,
                                                const u16* __restrict__ wsu,
                                                const float* __restrict__ b1,
                                                u16* __restrict__ E1H, u16* __restrict__ E1L) {
    __shared__ __align__(16) u16 uni[32256];       // 64.5 KB union
    u16* aAh = uni;                                // 16*720
    u16* aAl = uni + 11520;                        // 16*720
    u16* mAh = uni;                                // 16*6*168
    u16* mAl = uni + 16128;                        // 16*6*168
    const int tid = threadIdx.x;
    const int b0 = blockIdx.x << 4;
    // stage audio (split bf16, reflect pad)
    for (int i = tid; i < 16 * 160; i += 512) {
        int bb = i / 160, j4 = (i - bb * 160) * 4;
        const float* ap = audio + (size_t)(b0 + bb) * 576;
        float4 v;
        if (j4 < 576) v = *(const float4*)(ap + j4);
        else { v.x = ap[1150 - j4]; v.y = ap[1149 - j4]; v.z = ap[1148 - j4]; v.w = ap[1147 - j4]; }
        int phys = bb * 720 + j4 + (j4 >> 7) * 8;
        split_store4(v, aAh + phys, aAl + phys);
    }
    __syncthreads();
    const int lane = tid & 63, w = tid >> 6;
    const int m = lane & 15, quad = lane >> 4;
    // ---- GEMM1 (STFT): wave w owns nt = 2w..2w+1 (w==7 also nt=16), mt=4 ----
    const u16* fbT = wsu + P_FBT;
    const int tcnt = (w == 7) ? 3 : 2;
    f32x4 acc[4][3];
    #pragma unroll
    for (int mt = 0; mt < 4; ++mt)
        #pragma unroll
        for (int t = 0; t < 3; ++t) acc[mt][t] = (f32x4){0.f, 0.f, 0.f, 0.f};
    for (int ch = 0; ch < 8; ++ch) {
        bf16x8 ah[4], al[4];
        #pragma unroll
        for (int mt = 0; mt < 4; ++mt) {
            int Rm = mt * 16 + m;
            int phys = (Rm >> 2) * 720 + (Rm & 3) * 136 + ch * 32 + quad * 8 + ((ch >= 4) ? 8 : 0);
            ah[mt] = *(const bf16x8*)(aAh + phys);
            al[mt] = *(const bf16x8*)(aAl + phys);
        }
        #pragma unroll
        for (int tt = 0; tt < 3; ++tt) {
            if (tt < tcnt) {
                int t = w * 2 + tt;
                bf16x8 bh = bfrag(fbT, t, ch, 8, lane);
                bf16x8 bl_ = bfrag(fbT + S_FBT, t, ch, 8, lane);
                #pragma unroll
                for (int mt = 0; mt < 4; ++mt) {
                    acc[mt][tt] = MFMA(ah[mt], bh, acc[mt][tt]);
                    acc[mt][tt] = MFMA(ah[mt], bl_, acc[mt][tt]);
                    acc[mt][tt] = MFMA(al[mt], bh, acc[mt][tt]);
                }
            }
        }
    }
    __syncthreads();                                // audio reads done; safe to overwrite
    for (int i = tid; i < 16128; i += 512) ((u32*)uni)[i] = 0u;   // zero whole union (mag pads)
    __syncthreads();
    // magnitude epilogue -> mag LDS (split, aliased)
    #pragma unroll
    for (int tt = 0; tt < 3; ++tt) {
        if (tt < tcnt) {
            int n = (w * 2 + tt) * 16 + m;
            #pragma unroll
            for (int mt = 0; mt < 4; ++mt)
                #pragma unroll
                for (int r = 0; r < 4; ++r) {
                    float vv = acc[mt][tt][r];
                    float s = vv * vv;
                    s += __shfl_xor(s, 1);
                    if (!(n & 1)) {
                        int R = mt * 16 + quad * 4 + r;
                        int bb = R >> 2, t = R & 3, c = n >> 1;
                        float sv = sqrtf(s);
                        u16 h = f2bf(sv);
                        int phys = (bb * 6 + t + 1) * 168 + c;
                        mAh[phys] = h;
                        mAl[phys] = f2bf(sv - bf2f(h));
                    }
                }
        }
    }
    __syncthreads();
    // ---- GEMM2 (enc1): wave w owns nt = w (N=128), mt=4, K = 3 taps x 5 ch ----
    const u16* B1h = wsu + P_B1;
    const u16* B1l = wsu + P_B1 + S_B1;
    f32x4 acc2[4];
    #pragma unroll
    for (int mt = 0; mt < 4; ++mt) acc2[mt] = (f32x4){0.f, 0.f, 0.f, 0.f};
    for (int kk = 0; kk < 3; ++kk) {
        for (int ch = 0; ch < 5; ++ch) {
            bf16x8 bh = bfrag(B1h + kk * 20480, w, ch, 5, lane);
            bf16x8 bl_ = bfrag(B1l + kk * 20480, w, ch, 5, lane);
            #pragma unroll
            for (int mt = 0; mt < 4; ++mt) {
                int Rm = mt * 16 + m;
                int phys = ((Rm >> 2) * 6 + (Rm & 3) + kk) * 168 + ch * 32 + quad * 8;
                bf16x8 ah = *(const bf16x8*)(mAh + phys);
                bf16x8 al = *(const bf16x8*)(mAl + phys);
                acc2[mt] = MFMA(ah, bh, acc2[mt]);
                acc2[mt] = MFMA(ah, bl_, acc2[mt]);
                acc2[mt] = MFMA(al, bh, acc2[mt]);
            }
        }
    }
    {
        int n = w * 16 + m;
        float bv = b1[n];
        #pragma unroll
        for (int mt = 0; mt < 4; ++mt)
            #pragma unroll
            for (int r = 0; r < 4; ++r) {
                int R = mt * 16 + quad * 4 + r;
                float vv = fmaxf(acc2[mt][r] + bv, 0.f);
                u16 h = f2bf(vv);
                size_t idx = (size_t)(b0 + (R >> 2)) * 512 + (R & 3) * 128 + n;
                E1H[idx] = h;
                E1L[idx] = f2bf(vv - bf2f(h));
            }
    }
}

// ---------------- k_fused2: enc2a/2b + enc3 + enc4 + LSTM + head, all in one block ----------------
// block 512 (8 waves), 16 batches (M=16), grid 512.
__global__ __launch_bounds__(512) void k_fused2(const u16* __restrict__ E1H, const u16* __restrict__ E1L,
                                                const float* __restrict__ hin,
                                                const u16* __restrict__ wsu,
                                                const float* __restrict__ cin,
                                                const float* __restrict__ b2, const float* __restrict__ b3,
                                                const float* __restrict__ b4,
                                                const float* __restrict__ bxi, const float* __restrict__ bxf,
                                                const float* __restrict__ bxg, const float* __restrict__ bxo,
                                                const float* __restrict__ bhi, const float* __restrict__ bhf,
                                                const float* __restrict__ bhg, const float* __restrict__ bho,
                                                const float* __restrict__ cw, const float* __restrict__ cb,
                                                float* __restrict__ out) {
    __shared__ __align__(16) u16 eAh[16 * 520];
    __shared__ __align__(16) u16 eAl[16 * 520];
    __shared__ __align__(16) u16 s2h[16 * 136];
    __shared__ __align__(16) u16 s2l[16 * 136];
    __shared__ __align__(16) u16 s3h[16 * 72];
    __shared__ __align__(16) u16 s3l[16 * 72];
    __shared__ __align__(16) u16 xhh[16 * 264];
    __shared__ __align__(16) u16 xhl[16 * 264];
    __shared__ float pr[8][16];
    const int tid = threadIdx.x;
    const int b0 = blockIdx.x << 4;
    // stage e1 rows (plain u16 copies; already split)
    for (int i = tid; i < 16 * 64; i += 512) {
        int row = i >> 6, c8 = (i & 63) * 8;
        *(uint4*)(eAh + row * 520 + c8) = *(const uint4*)(E1H + (size_t)(b0 + row) * 512 + c8);
        *(uint4*)(eAl + row * 520 + c8) = *(const uint4*)(E1L + (size_t)(b0 + row) * 512 + c8);
    }
    // stage h (split) into xh cols 128..255
    for (int i = tid; i < 16 * 32; i += 512) {
        int row = i >> 5, c4 = (i & 31) * 4;
        float4 v = *(const float4*)(hin + (size_t)(b0 + row) * 128 + c4);
        split_store4(v, xhh + row * 264 + 128 + c4, xhl + row * 264 + 128 + c4);
    }
    __syncthreads();
    const int lane = tid & 63, w = tid >> 6;
    const int m = lane & 15, quad = lane >> 4;
    // ---- enc2: waves 0-3 = enc2a (K=256), waves 4-7 = enc2b (K=384) ----
    {
        const int isB = w >> 2, nt = w & 3;
        const int awoff = isB ? 128 : 0;
        const int nch = isB ? 12 : 8;
        const u16* Bh = wsu + (isB ? P_B2B : P_B2A);
        const u16* Bl = Bh + (isB ? S_B2B : S_B2A);
        f32x4 acc = (f32x4){0.f, 0.f, 0.f, 0.f};
        for (int ch = 0; ch < nch; ++ch) {
            int phys = m * 520 + awoff + ch * 32 + quad * 8;
            bf16x8 ah = *(const bf16x8*)(eAh + phys);
            bf16x8 al = *(const bf16x8*)(eAl + phys);
            bf16x8 bh = bfrag(Bh, nt, ch, nch, lane);
            bf16x8 bl_ = bfrag(Bl, nt, ch, nch, lane);
            acc = MFMA(ah, bh, acc);
            acc = MFMA(ah, bl_, acc);
            acc = MFMA(al, bh, acc);
        }
        const int oc = nt * 16 + m;
        const float bv = b2[oc];
        const int col = isB * 64 + oc;
        #pragma unroll
        for (int r = 0; r < 4; ++r) {
            int row = quad * 4 + r;
            float vv = fmaxf(acc[r] + bv, 0.f);
            u16 h = f2bf(vv);
            s2h[row * 136 + col] = h;
            s2l[row * 136 + col] = f2bf(vv - bf2f(h));
        }
    }
    __syncthreads();
    // ---- enc3: waves 0-3, K=128 (4 ch), N=64 ----
    if (w < 4) {
        const u16* Bh = wsu + P_B3;
        const u16* Bl = Bh + S_B3;
        f32x4 acc = (f32x4){0.f, 0.f, 0.f, 0.f};
        for (int ch = 0; ch < 4; ++ch) {
            int phys = m * 136 + ch * 32 + quad * 8;
            bf16x8 ah = *(const bf16x8*)(s2h + phys);
            bf16x8 al = *(const bf16x8*)(s2l + phys);
            bf16x8 bh = bfrag(Bh, w, ch, 4, lane);
            bf16x8 bl_ = bfrag(Bl, w, ch, 4, lane);
            acc = MFMA(ah, bh, acc);
            acc = MFMA(ah, bl_, acc);
            acc = MFMA(al, bh, acc);
        }
        const int n = w * 16 + m;
        const float bv = b3[n];
        #pragma unroll
        for (int r = 0; r < 4; ++r) {
            int row = quad * 4 + r;
            float vv = fmaxf(acc[r] + bv, 0.f);
            u16 h = f2bf(vv);
            s3h[row * 72 + n] = h;
            s3l[row * 72 + n] = f2bf(vv - bf2f(h));
        }
    }
    __syncthreads();
    // ---- enc4: all 8 waves, K=64 (2 ch), N=128 -> x into xh cols 0..127 ----
    {
        const u16* Bh = wsu + P_B4;
        const u16* Bl = Bh + S_B4;
        f32x4 acc = (f32x4){0.f, 0.f, 0.f, 0.f};
        for (int ch = 0; ch < 2; ++ch) {
            int phys = m * 72 + ch * 32 + quad * 8;
            bf16x8 ah = *(const bf16x8*)(s3h + phys);
            bf16x8 al = *(const bf16x8*)(s3l + phys);
            bf16x8 bh = bfrag(Bh, w, ch, 2, lane);
            bf16x8 bl_ = bfrag(Bl, w, ch, 2, lane);
            acc = MFMA(ah, bh, acc);
            acc = MFMA(ah, bl_, acc);
            acc = MFMA(al, bh, acc);
        }
        const int n = w * 16 + m;
        const float bv = b4[n];
        #pragma unroll
        for (int r = 0; r < 4; ++r) {
            int row = quad * 4 + r;
            float vv = fmaxf(acc[r] + bv, 0.f);
            u16 h = f2bf(vv);
            xhh[row * 264 + n] = h;
            xhl[row * 264 + n] = f2bf(vv - bf2f(h));
        }
    }
    __syncthreads();
    // ---- LSTM: wave w owns j-tile w x all 4 gates; K=256 (8 ch) ----
    {
        const u16* BLh = wsu + P_BL;
        const u16* BLl = BLh + S_BL;
        f32x4 acc[4];
        #pragma unroll
        for (int g = 0; g < 4; ++g) acc[g] = (f32x4){0.f, 0.f, 0.f, 0.f};
        for (int ch = 0; ch < 8; ++ch) {
            int phys = m * 264 + ch * 32 + quad * 8;
            bf16x8 ah = *(const bf16x8*)(xhh + phys);
            bf16x8 al = *(const bf16x8*)(xhl + phys);
            #pragma unroll
            for (int g = 0; g < 4; ++g) {
                int nt = g * 8 + w;
                bf16x8 bh = bfrag(BLh, nt, ch, 8, lane);
                bf16x8 bl_ = bfrag(BLl, nt, ch, 8, lane);
                acc[g] = MFMA(ah, bh, acc[g]);
                acc[g] = MFMA(ah, bl_, acc[g]);
                acc[g] = MFMA(al, bh, acc[g]);
            }
        }
        float partial[4];
        const int j = w * 16 + m;
        const float bi = bxi[j] + bhi[j];
        const float bff = bxf[j] + bhf[j];
        const float bgg = bxg[j] + bhg[j];
        const float boo = bxo[j] + bho[j];
        const float cwj = cw[j];
        #pragma unroll
        for (int r = 0; r < 4; ++r) {
            const int b = b0 + quad * 4 + r;
            const float ig = sigm(acc[0][r] + bi);
            const float fg = sigm(acc[1][r] + bff);
            const float gg = tanhf(acc[2][r] + bgg);
            const float og = sigm(acc[3][r] + boo);
            const float ci = cin[(size_t)b * 128 + j];
            const float co = fg * ci + ig * gg;
            const float ho = og * tanhf(co);
            out[(size_t)BATCH + (size_t)b * 128 + j] = ho;
            out[(size_t)BATCH + (size_t)BATCH * 128 + (size_t)b * 128 + j] = co;
            partial[r] = fmaxf(ho, 0.f) * cwj;
        }
        #pragma unroll
        for (int off = 1; off < 16; off <<= 1)
            #pragma unroll
            for (int r = 0; r < 4; ++r) partial[r] += __shfl_xor(partial[r], off);
        if (m == 0) {
            #pragma unroll
            for (int r = 0; r < 4; ++r) pr[w][quad * 4 + r] = partial[r];
        }
    }
    __syncthreads();
    if (tid < 16) {
        float s = cb[0];
        #pragma unroll
        for (int g = 0; g < 8; ++g) s += pr[g][tid];
        out[b0 + tid] = sigm(s);
    }
}

extern "C" void kernel_launch(void* const* d_in, const int* in_sizes, int n_in,
                              void* d_out, int out_size, void* d_ws, size_t ws_size,
                              hipStream_t stream) {
    const float* audio = (const float*)d_in[0];
    const float* hin   = (const float*)d_in[1];
    const float* cin   = (const float*)d_in[2];
    const float* fb    = (const float*)d_in[3];
    const float* w1    = (const float*)d_in[4];
    const float* b1    = (const float*)d_in[5];
    const float* w2    = (const float*)d_in[6];
    const float* b2    = (const float*)d_in[7];
    const float* w3    = (const float*)d_in[8];
    const float* b3    = (const float*)d_in[9];
    const float* w4    = (const float*)d_in[10];
    const float* b4    = (const float*)d_in[11];
    const float* wi    = (const float*)d_in[12];
    const float* wf    = (const float*)d_in[13];
    const float* wg    = (const float*)d_in[14];
    const float* wo    = (const float*)d_in[15];
    const float* ui    = (const float*)d_in[16];
    const float* uf    = (const float*)d_in[17];
    const float* ug    = (const float*)d_in[18];
    const float* uo    = (const float*)d_in[19];
    const float* bxi   = (const float*)d_in[20];
    const float* bxf   = (const float*)d_in[21];
    const float* bxg   = (const float*)d_in[22];
    const float* bxo   = (const float*)d_in[23];
    const float* bhi   = (const float*)d_in[24];
    const float* bhf   = (const float*)d_in[25];
    const float* bhg   = (const float*)d_in[26];
    const float* bho   = (const float*)d_in[27];
    const float* cw    = (const float*)d_in[28];
    const float* cb    = (const float*)d_in[29];
    float* out = (float*)d_out;

    u16* wsu = (u16*)d_ws;
    u16* E1H = wsu + WEND;
    u16* E1L = E1H + (size_t)BATCH * 512;

    k_prep<<<640, 256, 0, stream>>>(fb, w1, w2, w3, w4, wi, wf, wg, wo, ui, uf, ug, uo, wsu);
    k_fused1<<<BATCH / 16, 512, 0, stream>>>(audio, wsu, b1, E1H, E1L);
    k_fused2<<<BATCH / 16, 512, 0, stream>>>(E1H, E1L, hin, wsu, cin, b2, b3, b4,
                                             bxi, bxf, bxg, bxo, bhi, bhf, bhg, bho,
                                             cw, cb, out);
}

// Round 9
// 172.252 us; speedup vs baseline: 5.7336x; 1.0533x over previous
//
#include <hip/hip_runtime.h>
#include <math.h>

#define BATCH 8192
typedef unsigned short u16;
typedef unsigned int u32;
typedef __attribute__((ext_vector_type(8))) short bf16x8;
typedef __attribute__((ext_vector_type(4))) float f32x4;
typedef __attribute__((ext_vector_type(4))) unsigned short u16x4;

__device__ __forceinline__ float sigm(float v) { return 1.0f / (1.0f + __expf(-v)); }
__device__ __forceinline__ u16 f2bf(float f) {
    union { float f; u32 u; } v; v.f = f;
    u32 r = v.u + 0x7FFFu + ((v.u >> 16) & 1u);   // RNE
    return (u16)(r >> 16);
}
__device__ __forceinline__ float bf2f(u16 h) {
    union { u32 u; float f; } v; v.u = ((u32)h) << 16; return v.f;
}
__device__ __forceinline__ void split_store4(float4 v, u16* hp, u16* lp) {
    u16 h0 = f2bf(v.x), h1 = f2bf(v.y), h2 = f2bf(v.z), h3 = f2bf(v.w);
    u16x4 hv = {h0, h1, h2, h3};
    u16x4 lv = {f2bf(v.x - bf2f(h0)), f2bf(v.y - bf2f(h1)),
                f2bf(v.z - bf2f(h2)), f2bf(v.w - bf2f(h3))};
    *(u16x4*)hp = hv; *(u16x4*)lp = lv;
}
// fragment-linear B: element [(nt*nch + ch)*64 + lane]*8 + e  ==  B[nt*16+(lane&15)][ch*32+(lane>>4)*8+e]
__device__ __forceinline__ bf16x8 bfrag(const u16* Bf, int nt, int ch, int nch, int lane) {
    return *(const bf16x8*)(Bf + (((size_t)nt * nch + ch) * 64 + lane) * 8);
}
#define MFMA(a, b, c) __builtin_amdgcn_mfma_f32_16x16x32_bf16(a, b, c, 0, 0, 0)

// ---------------- workspace layout (u16 elements); hi plane then lo plane ----------------
#define S_FBT 69632   // [17 nt][8 ch] frag-linear, n<272, k<256
#define S_B1  61440   // 3 taps x [8 nt][5 ch], n<128, k<160
#define S_B2A 16384   // [4 nt][8 ch]
#define S_B2B 24576   // [4 nt][12 ch]
#define S_B3  8192    // [4 nt][4 ch]
#define S_B4  8192    // [8 nt][2 ch]
#define S_BL  131072  // [32 nt][8 ch]  n = gate*128+j, k: 0..127 W / 128..255 U
#define P_FBT 0
#define P_B1  139264
#define P_B2A 262144
#define P_B2B 294912
#define P_B3  344064
#define P_B4  360448
#define P_BL  376832
#define N_PREP 319488

// ---------------- k_prep: build fragment-linear split-bf16 B planes ----------------
__global__ __launch_bounds__(256) void k_prep(const float* __restrict__ fb,
                                              const float* __restrict__ w1, const float* __restrict__ w2,
                                              const float* __restrict__ w3, const float* __restrict__ w4,
                                              const float* __restrict__ wi, const float* __restrict__ wf,
                                              const float* __restrict__ wg, const float* __restrict__ wo,
                                              const float* __restrict__ ui, const float* __restrict__ uf,
                                              const float* __restrict__ ug, const float* __restrict__ uo,
                                              u16* __restrict__ wsu) {
    const float* Ws[8] = {wi, wf, wg, wo, ui, uf, ug, uo};
    for (int i = blockIdx.x * 256 + threadIdx.x; i < N_PREP; i += gridDim.x * 256) {
        int r = i;
        float v; int P, S, idx;
        if (r < S_FBT) {                                    // FBT nch=8
            int f = r >> 9, lane = (r & 511) >> 3, e = r & 7;
            int n = (f >> 3) * 16 + (lane & 15), k = (f & 7) * 32 + (lane >> 4) * 8 + e;
            int c = n >> 1, part = n & 1;
            v = (n < 258) ? fb[(size_t)(c + part * 129) * 256 + k] : 0.f;
            P = P_FBT; S = S_FBT; idx = r;
        } else if ((r -= S_FBT) < S_B1) {                   // B1: 3 taps, nch=5
            int kk = r / 20480, r2 = r - kk * 20480;
            int f = r2 >> 9, lane = (r2 & 511) >> 3, e = r2 & 7;
            int n = (f / 5) * 16 + (lane & 15), k = (f % 5) * 32 + (lane >> 4) * 8 + e;
            v = (k < 129) ? w1[(size_t)n * 387 + k * 3 + kk] : 0.f;
            P = P_B1; S = S_B1; idx = r;
        } else if ((r -= S_B1) < S_B2A) {                   // B2A nch=8
            int f = r >> 9, lane = (r & 511) >> 3, e = r & 7;
            int n = (f >> 3) * 16 + (lane & 15), k = (f & 7) * 32 + (lane >> 4) * 8 + e;
            v = w2[(size_t)n * 384 + (k & 127) * 3 + (k >> 7) + 1];
            P = P_B2A; S = S_B2A; idx = r;
        } else if ((r -= S_B2A) < S_B2B) {                  // B2B nch=12
            int f = r >> 9, lane = (r & 511) >> 3, e = r & 7;
            int n = (f / 12) * 16 + (lane & 15), k = (f % 12) * 32 + (lane >> 4) * 8 + e;
            v = w2[(size_t)n * 384 + (k & 127) * 3 + (k >> 7)];
            P = P_B2B; S = S_B2B; idx = r;
        } else if ((r -= S_B2B) < S_B3) {                   // B3 nch=4
            int f = r >> 9, lane = (r & 511) >> 3, e = r & 7;
            int n = (f >> 2) * 16 + (lane & 15), k = (f & 3) * 32 + (lane >> 4) * 8 + e;
            v = w3[(size_t)n * 192 + (k & 63) * 3 + (k >> 6) + 1];
            P = P_B3; S = S_B3; idx = r;
        } else if ((r -= S_B3) < S_B4) {                    // B4 nch=2
            int f = r >> 9, lane = (r & 511) >> 3, e = r & 7;
            int n = (f >> 1) * 16 + (lane & 15), k = (f & 1) * 32 + (lane >> 4) * 8 + e;
            v = w4[(size_t)n * 192 + k * 3 + 1];
            P = P_B4; S = S_B4; idx = r;
        } else {                                            // BL nch=8
            r -= S_B4;
            int f = r >> 9, lane = (r & 511) >> 3, e = r & 7;
            int n = (f >> 3) * 16 + (lane & 15), k = (f & 7) * 32 + (lane >> 4) * 8 + e;
            int g = n >> 7, j = n & 127;
            v = Ws[g + ((k >= 128) ? 4 : 0)][(size_t)j * 128 + (k & 127)];
            P = P_BL; S = S_BL; idx = r;
        }
        u16 h = f2bf(v);
        wsu[P + idx] = h;
        wsu[P + S + idx] = f2bf(v - bf2f(h));
    }
}

// ---------------- k_all: STFT -> mag -> enc1 -> enc2 -> enc3 -> enc4 -> LSTM -> head ----------------
// block 512 (8 waves), 16 batches (64 stft rows, mt=4), grid 512 (= 2 blocks/CU).
// LDS union (u16), time-multiplexed:
//   phase A: audio  aAh[0,11520) aAl[11520,23040)   stride 720 (conflict-free)
//   phase B: mag    mAh[0,16128) mAl[16128,32256)   rows bb*6+tp, stride 168
//   phase C: e1     eAh[0,8320)  eAl[8320,16640)    rows=batch, stride 520
//            s2 [16640,20992) s3 [20992,23296) xh [23296,31744) pr [31744,32256)
__global__ __launch_bounds__(512) void k_all(const float* __restrict__ audio,
                                             const u16* __restrict__ wsu,
                                             const float* __restrict__ hin, const float* __restrict__ cin,
                                             const float* __restrict__ b1, const float* __restrict__ b2,
                                             const float* __restrict__ b3, const float* __restrict__ b4,
                                             const float* __restrict__ bxi, const float* __restrict__ bxf,
                                             const float* __restrict__ bxg, const float* __restrict__ bxo,
                                             const float* __restrict__ bhi, const float* __restrict__ bhf,
                                             const float* __restrict__ bhg, const float* __restrict__ bho,
                                             const float* __restrict__ cw, const float* __restrict__ cb,
                                             float* __restrict__ out) {
    __shared__ __align__(16) u16 uni[32256];
    u16* aAh = uni;
    u16* aAl = uni + 11520;
    u16* mAh = uni;
    u16* mAl = uni + 16128;
    u16* eAh = uni;
    u16* eAl = uni + 8320;
    u16* s2h = uni + 16640;
    u16* s2l = uni + 18816;
    u16* s3h = uni + 20992;
    u16* s3l = uni + 22144;
    u16* xhh = uni + 23296;
    u16* xhl = uni + 27520;
    float* pr = (float*)(uni + 31744);
    const int tid = threadIdx.x;
    const int b0 = blockIdx.x << 4;
    // ---- phase A: stage audio (split bf16, reflect pad) ----
    for (int i = tid; i < 16 * 160; i += 512) {
        int bb = i / 160, j4 = (i - bb * 160) * 4;
        const float* ap = audio + (size_t)(b0 + bb) * 576;
        float4 v;
        if (j4 < 576) v = *(const float4*)(ap + j4);
        else { v.x = ap[1150 - j4]; v.y = ap[1149 - j4]; v.z = ap[1148 - j4]; v.w = ap[1147 - j4]; }
        int phys = bb * 720 + j4 + (j4 >> 7) * 8;
        split_store4(v, aAh + phys, aAl + phys);
    }
    __syncthreads();
    const int lane = tid & 63, w = tid >> 6;
    const int m = lane & 15, quad = lane >> 4;
    // ---- GEMM1 (STFT): wave w owns nt = 2w..2w+1 (w==7 also nt=16), mt=4 ----
    const u16* fbT = wsu + P_FBT;
    const int tcnt = (w == 7) ? 3 : 2;
    f32x4 acc[4][3];
    #pragma unroll
    for (int mt = 0; mt < 4; ++mt)
        #pragma unroll
        for (int t = 0; t < 3; ++t) acc[mt][t] = (f32x4){0.f, 0.f, 0.f, 0.f};
    for (int ch = 0; ch < 8; ++ch) {
        bf16x8 ah[4], al[4];
        #pragma unroll
        for (int mt = 0; mt < 4; ++mt) {
            int Rm = mt * 16 + m;
            int phys = (Rm >> 2) * 720 + (Rm & 3) * 136 + ch * 32 + quad * 8 + ((ch >= 4) ? 8 : 0);
            ah[mt] = *(const bf16x8*)(aAh + phys);
            al[mt] = *(const bf16x8*)(aAl + phys);
        }
        #pragma unroll
        for (int tt = 0; tt < 3; ++tt) {
            if (tt < tcnt) {
                int t = w * 2 + tt;
                bf16x8 bh = bfrag(fbT, t, ch, 8, lane);
                bf16x8 bl_ = bfrag(fbT + S_FBT, t, ch, 8, lane);
                #pragma unroll
                for (int mt = 0; mt < 4; ++mt) {
                    acc[mt][tt] = MFMA(ah[mt], bh, acc[mt][tt]);
                    acc[mt][tt] = MFMA(ah[mt], bl_, acc[mt][tt]);
                    acc[mt][tt] = MFMA(al[mt], bh, acc[mt][tt]);
                }
            }
        }
    }
    __syncthreads();                                // audio dead
    for (int i = tid; i < 16128; i += 512) ((u32*)uni)[i] = 0u;   // zero union (mag pads)
    __syncthreads();
    // ---- magnitude epilogue -> mag LDS ----
    #pragma unroll
    for (int tt = 0; tt < 3; ++tt) {
        if (tt < tcnt) {
            int n = (w * 2 + tt) * 16 + m;
            #pragma unroll
            for (int mt = 0; mt < 4; ++mt)
                #pragma unroll
                for (int r = 0; r < 4; ++r) {
                    float vv = acc[mt][tt][r];
                    float s = vv * vv;
                    s += __shfl_xor(s, 1);
                    if (!(n & 1)) {
                        int R = mt * 16 + quad * 4 + r;
                        int bb = R >> 2, t = R & 3, c = n >> 1;
                        float sv = sqrtf(s);
                        u16 h = f2bf(sv);
                        int phys = (bb * 6 + t + 1) * 168 + c;
                        mAh[phys] = h;
                        mAl[phys] = f2bf(sv - bf2f(h));
                    }
                }
        }
    }
    __syncthreads();
    // ---- GEMM2 (enc1): wave w owns nt = w (N=128), mt=4, K = 3 taps x 5 ch ----
    const u16* B1h = wsu + P_B1;
    const u16* B1l = wsu + P_B1 + S_B1;
    f32x4 acc2[4];
    #pragma unroll
    for (int mt = 0; mt < 4; ++mt) acc2[mt] = (f32x4){0.f, 0.f, 0.f, 0.f};
    for (int kk = 0; kk < 3; ++kk) {
        for (int ch = 0; ch < 5; ++ch) {
            bf16x8 bh = bfrag(B1h + kk * 20480, w, ch, 5, lane);
            bf16x8 bl_ = bfrag(B1l + kk * 20480, w, ch, 5, lane);
            #pragma unroll
            for (int mt = 0; mt < 4; ++mt) {
                int Rm = mt * 16 + m;
                int phys = ((Rm >> 2) * 6 + (Rm & 3) + kk) * 168 + ch * 32 + quad * 8;
                bf16x8 ah = *(const bf16x8*)(mAh + phys);
                bf16x8 al = *(const bf16x8*)(mAl + phys);
                acc2[mt] = MFMA(ah, bh, acc2[mt]);
                acc2[mt] = MFMA(ah, bl_, acc2[mt]);
                acc2[mt] = MFMA(al, bh, acc2[mt]);
            }
        }
    }
    __syncthreads();                                // mag dead
    // ---- e1 -> LDS (split), h -> xh cols 128..255 ----
    {
        int n = w * 16 + m;
        float bv = b1[n];
        #pragma unroll
        for (int mt = 0; mt < 4; ++mt)
            #pragma unroll
            for (int r = 0; r < 4; ++r) {
                int R = mt * 16 + quad * 4 + r;
                float vv = fmaxf(acc2[mt][r] + bv, 0.f);
                u16 h = f2bf(vv);
                int phys = (R >> 2) * 520 + (R & 3) * 128 + n;
                eAh[phys] = h;
                eAl[phys] = f2bf(vv - bf2f(h));
            }
    }
    for (int i = tid; i < 16 * 32; i += 512) {
        int row = i >> 5, c4 = (i & 31) * 4;
        float4 v = *(const float4*)(hin + (size_t)(b0 + row) * 128 + c4);
        split_store4(v, xhh + row * 264 + 128 + c4, xhl + row * 264 + 128 + c4);
    }
    __syncthreads();
    // ---- enc2: waves 0-3 = enc2a (K=256), waves 4-7 = enc2b (K=384) ----
    {
        const int isB = w >> 2, nt = w & 3;
        const int awoff = isB ? 128 : 0;
        const int nch = isB ? 12 : 8;
        const u16* Bh = wsu + (isB ? P_B2B : P_B2A);
        const u16* Bl = Bh + (isB ? S_B2B : S_B2A);
        f32x4 a2 = (f32x4){0.f, 0.f, 0.f, 0.f};
        for (int ch = 0; ch < nch; ++ch) {
            int phys = m * 520 + awoff + ch * 32 + quad * 8;
            bf16x8 ah = *(const bf16x8*)(eAh + phys);
            bf16x8 al = *(const bf16x8*)(eAl + phys);
            bf16x8 bh = bfrag(Bh, nt, ch, nch, lane);
            bf16x8 bl_ = bfrag(Bl, nt, ch, nch, lane);
            a2 = MFMA(ah, bh, a2);
            a2 = MFMA(ah, bl_, a2);
            a2 = MFMA(al, bh, a2);
        }
        const int oc = nt * 16 + m;
        const float bv = b2[oc];
        const int col = isB * 64 + oc;
        #pragma unroll
        for (int r = 0; r < 4; ++r) {
            int row = quad * 4 + r;
            float vv = fmaxf(a2[r] + bv, 0.f);
            u16 h = f2bf(vv);
            s2h[row * 136 + col] = h;
            s2l[row * 136 + col] = f2bf(vv - bf2f(h));
        }
    }
    __syncthreads();
    // ---- enc3: waves 0-3, K=128 (4 ch), N=64 ----
    if (w < 4) {
        const u16* Bh = wsu + P_B3;
        const u16* Bl = Bh + S_B3;
        f32x4 a3 = (f32x4){0.f, 0.f, 0.f, 0.f};
        for (int ch = 0; ch < 4; ++ch) {
            int phys = m * 136 + ch * 32 + quad * 8;
            bf16x8 ah = *(const bf16x8*)(s2h + phys);
            bf16x8 al = *(const bf16x8*)(s2l + phys);
            bf16x8 bh = bfrag(Bh, w, ch, 4, lane);
            bf16x8 bl_ = bfrag(Bl, w, ch, 4, lane);
            a3 = MFMA(ah, bh, a3);
            a3 = MFMA(ah, bl_, a3);
            a3 = MFMA(al, bh, a3);
        }
        const int n = w * 16 + m;
        const float bv = b3[n];
        #pragma unroll
        for (int r = 0; r < 4; ++r) {
            int row = quad * 4 + r;
            float vv = fmaxf(a3[r] + bv, 0.f);
            u16 h = f2bf(vv);
            s3h[row * 72 + n] = h;
            s3l[row * 72 + n] = f2bf(vv - bf2f(h));
        }
    }
    __syncthreads();
    // ---- enc4: all 8 waves, K=64 (2 ch), N=128 -> x into xh cols 0..127 ----
    {
        const u16* Bh = wsu + P_B4;
        const u16* Bl = Bh + S_B4;
        f32x4 a4 = (f32x4){0.f, 0.f, 0.f, 0.f};
        for (int ch = 0; ch < 2; ++ch) {
            int phys = m * 72 + ch * 32 + quad * 8;
            bf16x8 ah = *(const bf16x8*)(s3h + phys);
            bf16x8 al = *(const bf16x8*)(s3l + phys);
            bf16x8 bh = bfrag(Bh, w, ch, 2, lane);
            bf16x8 bl_ = bfrag(Bl, w, ch, 2, lane);
            a4 = MFMA(ah, bh, a4);
            a4 = MFMA(ah, bl_, a4);
            a4 = MFMA(al, bh, a4);
        }
        const int n = w * 16 + m;
        const float bv = b4[n];
        #pragma unroll
        for (int r = 0; r < 4; ++r) {
            int row = quad * 4 + r;
            float vv = fmaxf(a4[r] + bv, 0.f);
            u16 h = f2bf(vv);
            xhh[row * 264 + n] = h;
            xhl[row * 264 + n] = f2bf(vv - bf2f(h));
        }
    }
    __syncthreads();
    // ---- LSTM: wave w owns j-tile w x all 4 gates; K=256 (8 ch) ----
    {
        const u16* BLh = wsu + P_BL;
        const u16* BLl = BLh + S_BL;
        f32x4 ag[4];
        #pragma unroll
        for (int g = 0; g < 4; ++g) ag[g] = (f32x4){0.f, 0.f, 0.f, 0.f};
        #pragma unroll 2
        for (int ch = 0; ch < 8; ++ch) {
            int phys = m * 264 + ch * 32 + quad * 8;
            bf16x8 ah = *(const bf16x8*)(xhh + phys);
            bf16x8 al = *(const bf16x8*)(xhl + phys);
            #pragma unroll
            for (int g = 0; g < 4; ++g) {
                int nt = g * 8 + w;
                bf16x8 bh = bfrag(BLh, nt, ch, 8, lane);
                bf16x8 bl_ = bfrag(BLl, nt, ch, 8, lane);
                ag[g] = MFMA(ah, bh, ag[g]);
                ag[g] = MFMA(ah, bl_, ag[g]);
                ag[g] = MFMA(al, bh, ag[g]);
            }
        }
        float partial[4];
        const int j = w * 16 + m;
        const float bi = bxi[j] + bhi[j];
        const float bff = bxf[j] + bhf[j];
        const float bgg = bxg[j] + bhg[j];
        const float boo = bxo[j] + bho[j];
        const float cwj = cw[j];
        #pragma unroll
        for (int r = 0; r < 4; ++r) {
            const int b = b0 + quad * 4 + r;
            const float ig = sigm(ag[0][r] + bi);
            const float fg = sigm(ag[1][r] + bff);
            const float gg = tanhf(ag[2][r] + bgg);
            const float og = sigm(ag[3][r] + boo);
            const float ci = cin[(size_t)b * 128 + j];
            const float co = fg * ci + ig * gg;
            const float ho = og * tanhf(co);
            out[(size_t)BATCH + (size_t)b * 128 + j] = ho;
            out[(size_t)BATCH + (size_t)BATCH * 128 + (size_t)b * 128 + j] = co;
            partial[r] = fmaxf(ho, 0.f) * cwj;
        }
        #pragma unroll
        for (int off = 1; off < 16; off <<= 1)
            #pragma unroll
            for (int r = 0; r < 4; ++r) partial[r] += __shfl_xor(partial[r], off);
        if (m == 0) {
            #pragma unroll
            for (int r = 0; r < 4; ++r) pr[w * 16 + quad * 4 + r] = partial[r];
        }
    }
    __syncthreads();
    if (tid < 16) {
        float s = cb[0];
        #pragma unroll
        for (int g = 0; g < 8; ++g) s += pr[g * 16 + tid];
        out[b0 + tid] = sigm(s);
    }
}

extern "C" void kernel_launch(void* const* d_in, const int* in_sizes, int n_in,
                              void* d_out, int out_size, void* d_ws, size_t ws_size,
                              hipStream_t stream) {
    const float* audio = (const float*)d_in[0];
    const float* hin   = (const float*)d_in[1];
    const float* cin   = (const float*)d_in[2];
    const float* fb    = (const float*)d_in[3];
    const float* w1    = (const float*)d_in[4];
    const float* b1    = (const float*)d_in[5];
    const float* w2    = (const float*)d_in[6];
    const float* b2    = (const float*)d_in[7];
    const float* w3    = (const float*)d_in[8];
    const float* b3    = (const float*)d_in[9];
    const float* w4    = (const float*)d_in[10];
    const float* b4    = (const float*)d_in[11];
    const float* wi    = (const float*)d_in[12];
    const float* wf    = (const float*)d_in[13];
    const float* wg    = (const float*)d_in[14];
    const float* wo    = (const float*)d_in[15];
    const float* ui    = (const float*)d_in[16];
    const float* uf    = (const float*)d_in[17];
    const float* ug    = (const float*)d_in[18];
    const float* uo    = (const float*)d_in[19];
    const float* bxi   = (const float*)d_in[20];
    const float* bxf   = (const float*)d_in[21];
    const float* bxg   = (const float*)d_in[22];
    const float* bxo   = (const float*)d_in[23];
    const float* bhi   = (const float*)d_in[24];
    const float* bhf   = (const float*)d_in[25];
    const float* bhg   = (const float*)d_in[26];
    const float* bho   = (const float*)d_in[27];
    const float* cw    = (const float*)d_in[28];
    const float* cb    = (const float*)d_in[29];
    float* out = (float*)d_out;

    u16* wsu = (u16*)d_ws;

    k_prep<<<640, 256, 0, stream>>>(fb, w1, w2, w3, w4, wi, wf, wg, wo, ui, uf, ug, uo, wsu);
    k_all<<<BATCH / 16, 512, 0, stream>>>(audio, wsu, hin, cin, b1, b2, b3, b4,
                                          bxi, bxf, bxg, bxo, bhi, bhf, bhg, bho,
                                          cw, cb, out);
}